// Round 1
// baseline (1250.484 us; speedup 1.0000x reference)
//
#include <hip/hip_runtime.h>

// Problem dims
constexpr int N_TOK = 2048;   // T*B
constexpr int C_    = 256;    // in features (== R == OUT)
constexpr int NE    = 64;     // experts
constexpr int D_    = 65536;  // R*OUT centroid dim
constexpr float DECAYF = 0.999f;
constexpr float OMD    = 0.001f;          // f32(1.0 - 0.999) as jnp uses
constexpr float ALPHA  = OMD / 2048.0f;   // (1-decay)/N
constexpr float RTHRESH = 1e-5f;          // routing weight cutoff (err <= 64*1e-5*|O| << 0.8)

// ---------- workspace layout (float offsets) ----------
// zero-initialized zone (atomically accumulated or conditionally written):
constexpr size_t OFF_S     = 0;        // 65536  S = X^T X
constexpr size_t OFF_XSUM  = 65536;    // 256
constexpr size_t OFF_G     = 65792;    // 65536  G = W^T W (blocks {00,01,11}; 10 left zero)
constexpr size_t OFF_M     = 131328;   // 16384  M = c @ W
constexpr size_t OFF_WB    = 147712;   // 256    Wb = b^T W
constexpr size_t OFF_BB    = 147968;   // 16     bb = ||b||^2
constexpr size_t OFF_SUMR  = 147984;   // 64     sum_n resp
constexpr size_t OFF_A     = 148048;   // 16384  A = resp^T X
constexpr size_t OFF_MNEW  = 164432;   // 16384  Mnew = cnew @ W
constexpr size_t OFF_CCN   = 180816;   // 4096   cnew cnew^T
constexpr size_t OFF_RR    = 184912;   // 4096   resp^T resp
constexpr size_t OFF_CBNEW = 189008;   // 64     cnew . b
constexpr size_t OFF_CNT   = 189072;   // 64     per-expert token counts (uint)
constexpr size_t OFF_CN2   = 189136;   // 64     ||c_e||^2
constexpr size_t OFF_CB    = 189200;   // 64     c_e . b
constexpr size_t ZFLOATS   = 189264;
// overwritten-before-read zone:
constexpr size_t OFF_RESP  = 189264;   // 131072
constexpr size_t OFF_Y     = 320336;   // 524288 y = X @ pw^T
constexpr size_t OFF_CNEW  = 844624;   // 4194304
constexpr size_t OFF_TIDX  = 5038928;  // 131072 (int) token lists
constexpr size_t OFF_TOKR  = 5170000;  // 131072 token resp values
// total = 5301072 floats = 21,204,288 bytes

// ---------------- centroid stats: cn2[e], cb[e] ----------------
__global__ __launch_bounds__(256) void k_cstats(const float* __restrict__ cen,
    const float* __restrict__ bmap, float* __restrict__ cn2, float* __restrict__ cb) {
  int e = blockIdx.x;
  const float* ce = cen + (size_t)e * D_;
  float s2 = 0.f, sb = 0.f;
  for (int d = threadIdx.x; d < D_; d += 256) {
    float v = ce[d];
    s2 = fmaf(v, v, s2);
    sb = fmaf(v, bmap[d], sb);
  }
  __shared__ float r0[256], r1[256];
  r0[threadIdx.x] = s2; r1[threadIdx.x] = sb;
  __syncthreads();
  for (int s = 128; s > 0; s >>= 1) {
    if (threadIdx.x < s) { r0[threadIdx.x] += r0[threadIdx.x + s];
                           r1[threadIdx.x] += r1[threadIdx.x + s]; }
    __syncthreads();
  }
  if (threadIdx.x == 0) { cn2[e] = r0[0]; cb[e] = r1[0]; }
}

// ---------------- bb = ||b||^2 ----------------
__global__ __launch_bounds__(256) void k_bb(const float* __restrict__ bmap, float* __restrict__ bb) {
  float s = 0.f;
  for (int d = threadIdx.x; d < D_; d += 256) { float v = bmap[d]; s = fmaf(v, v, s); }
  __shared__ float red[256];
  red[threadIdx.x] = s;
  __syncthreads();
  for (int k = 128; k > 0; k >>= 1) {
    if (threadIdx.x < k) red[threadIdx.x] += red[threadIdx.x + k];
    __syncthreads();
  }
  if (threadIdx.x == 0) bb[0] = red[0];
}

// ---------------- S = X^T X (32x32 tiles, k = 2048) ----------------
__global__ __launch_bounds__(256) void k_S(const float* __restrict__ x, float* __restrict__ S) {
  int c1t = blockIdx.y * 32, c2t = blockIdx.x * 32;
  __shared__ float Xa[32][33], Xb[32][33];
  int t = threadIdx.x;
  int tx = t & 15, ty = t >> 4;
  float acc[2][2] = {};
  int nn = t >> 3, cc = (t & 7) * 4;
  for (int n0 = 0; n0 < N_TOK; n0 += 32) {
    float4 va = *(const float4*)&x[(n0 + nn) * C_ + c1t + cc];
    float4 vb = *(const float4*)&x[(n0 + nn) * C_ + c2t + cc];
    __syncthreads();
    Xa[nn][cc] = va.x; Xa[nn][cc+1] = va.y; Xa[nn][cc+2] = va.z; Xa[nn][cc+3] = va.w;
    Xb[nn][cc] = vb.x; Xb[nn][cc+1] = vb.y; Xb[nn][cc+2] = vb.z; Xb[nn][cc+3] = vb.w;
    __syncthreads();
    #pragma unroll 8
    for (int n = 0; n < 32; n++) {
      float a0 = Xa[n][ty*2], a1 = Xa[n][ty*2+1];
      float b0 = Xb[n][tx*2], b1 = Xb[n][tx*2+1];
      acc[0][0] = fmaf(a0, b0, acc[0][0]); acc[0][1] = fmaf(a0, b1, acc[0][1]);
      acc[1][0] = fmaf(a1, b0, acc[1][0]); acc[1][1] = fmaf(a1, b1, acc[1][1]);
    }
  }
  #pragma unroll
  for (int i = 0; i < 2; i++)
    #pragma unroll
    for (int j = 0; j < 2; j++)
      S[(c1t + ty*2 + i) * C_ + c2t + tx*2 + j] = acc[i][j];
}

// ---------------- Xsum[c] = sum_n X[n,c] ----------------
__global__ __launch_bounds__(256) void k_xsum(const float* __restrict__ x, float* __restrict__ xsum) {
  int n0 = blockIdx.x * 64;
  int c = threadIdx.x;
  float s = 0.f;
  for (int n = 0; n < 64; n++) s += x[(n0 + n) * C_ + c];
  atomicAdd(&xsum[c], s);
}

// ---------------- G = W^T W, 128x128 tiles, pairs {00,01,11}, split-k atomics -----
__global__ __launch_bounds__(256) void k_G(const float* __restrict__ W, float* __restrict__ G) {
  const int p1tab[3] = {0, 0, 1};
  const int p2tab[3] = {0, 1, 1};
  int c1t = p1tab[blockIdx.y] * 128, c2t = p2tab[blockIdx.y] * 128;
  int d0 = blockIdx.x * 1024;
  __shared__ float Wa[8][132], Wb_[8][132];
  int t = threadIdx.x;
  int tx = t & 15, ty = t >> 4;
  int row = t >> 5, col = (t & 31) * 4;
  float acc[8][8] = {};
  for (int dk = 0; dk < 1024; dk += 8) {
    float4 va = *(const float4*)&W[(size_t)(d0 + dk + row) * C_ + c1t + col];
    float4 vb = *(const float4*)&W[(size_t)(d0 + dk + row) * C_ + c2t + col];
    __syncthreads();
    *(float4*)&Wa[row][col]  = va;
    *(float4*)&Wb_[row][col] = vb;
    __syncthreads();
    #pragma unroll
    for (int kk = 0; kk < 8; kk++) {
      float ra[8], rb[8];
      #pragma unroll
      for (int i = 0; i < 8; i++) ra[i] = Wa[kk][ty*8 + i];
      #pragma unroll
      for (int j = 0; j < 8; j++) rb[j] = Wb_[kk][tx*8 + j];
      #pragma unroll
      for (int i = 0; i < 8; i++)
        #pragma unroll
        for (int j = 0; j < 8; j++)
          acc[i][j] = fmaf(ra[i], rb[j], acc[i][j]);
    }
  }
  #pragma unroll
  for (int i = 0; i < 8; i++)
    #pragma unroll
    for (int j = 0; j < 8; j++)
      atomicAdd(&G[(c1t + ty*8 + i) * C_ + c2t + tx*8 + j], acc[i][j]);
}

// -------- Out[64,256] += Arows[64,D] @ W[D,256]   (used for M and Mnew) --------
__global__ __launch_bounds__(256) void k_mm64(const float* __restrict__ Arows,
    const float* __restrict__ W, float* __restrict__ Out) {
  int d0 = blockIdx.x * 1024;
  int c0 = blockIdx.y * 64;
  __shared__ float As[64][17];
  __shared__ float Bs[16][68];
  int t = threadIdx.x;
  int tx = t & 15, ty = t >> 4;
  int ea = t >> 2, k4 = (t & 3) * 4;
  int kb = t >> 4, cc4 = (t & 15) * 4;
  float acc[4][4] = {};
  for (int dk = 0; dk < 1024; dk += 16) {
    float4 va = *(const float4*)&Arows[(size_t)ea * D_ + d0 + dk + k4];
    float4 vb = *(const float4*)&W[(size_t)(d0 + dk + kb) * C_ + c0 + cc4];
    __syncthreads();
    As[ea][k4] = va.x; As[ea][k4+1] = va.y; As[ea][k4+2] = va.z; As[ea][k4+3] = va.w;
    *(float4*)&Bs[kb][cc4] = vb;
    __syncthreads();
    #pragma unroll
    for (int k = 0; k < 16; k++) {
      float ra[4], rb[4];
      #pragma unroll
      for (int i = 0; i < 4; i++) ra[i] = As[ty*4 + i][k];
      #pragma unroll
      for (int j = 0; j < 4; j++) rb[j] = Bs[k][tx*4 + j];
      #pragma unroll
      for (int i = 0; i < 4; i++)
        #pragma unroll
        for (int j = 0; j < 4; j++)
          acc[i][j] = fmaf(ra[i], rb[j], acc[i][j]);
    }
  }
  #pragma unroll
  for (int i = 0; i < 4; i++)
    #pragma unroll
    for (int j = 0; j < 4; j++)
      atomicAdd(&Out[(ty*4 + i) * C_ + c0 + tx*4 + j], acc[i][j]);
}

// ---------------- Wb[c] = sum_d b[d] W[d,c] (skips all-zero b chunks) ----------
__global__ __launch_bounds__(256) void k_Wb(const float* __restrict__ bmap,
    const float* __restrict__ W, float* __restrict__ Wb) {
  int d0 = blockIdx.x * 256;
  int c = threadIdx.x;
  __shared__ float bs[256];
  __shared__ int any;
  if (c == 0) any = 0;
  __syncthreads();
  float bv = bmap[d0 + c];
  bs[c] = bv;
  if (bv != 0.f) any = 1;
  __syncthreads();
  if (any == 0) return;
  float s = 0.f;
  for (int d = 0; d < 256; d++) s = fmaf(bs[d], W[(size_t)(d0 + d) * C_ + c], s);
  atomicAdd(&Wb[c], s);
}

// ---------------- y[n,k] = sum_j X[n,j] pw[k,j] ----------------
__global__ __launch_bounds__(256) void k_y(const float* __restrict__ x,
    const float* __restrict__ pw, float* __restrict__ y) {
  int n0 = blockIdx.x * 64, k0 = blockIdx.y * 64;
  __shared__ float Xs[64][17], Ps[64][17];
  int t = threadIdx.x;
  int tx = t & 15, ty = t >> 4;
  int r = t >> 2, q4 = (t & 3) * 4;
  float acc[4][4] = {};
  for (int j0 = 0; j0 < 256; j0 += 16) {
    float4 va = *(const float4*)&x[(n0 + r) * C_ + j0 + q4];
    float4 vb = *(const float4*)&pw[(k0 + r) * C_ + j0 + q4];
    __syncthreads();
    Xs[r][q4] = va.x; Xs[r][q4+1] = va.y; Xs[r][q4+2] = va.z; Xs[r][q4+3] = va.w;
    Ps[r][q4] = vb.x; Ps[r][q4+1] = vb.y; Ps[r][q4+2] = vb.z; Ps[r][q4+3] = vb.w;
    __syncthreads();
    #pragma unroll
    for (int k = 0; k < 16; k++) {
      float ra[4], rb[4];
      #pragma unroll
      for (int i = 0; i < 4; i++) ra[i] = Xs[ty*4 + i][k];
      #pragma unroll
      for (int j = 0; j < 4; j++) rb[j] = Ps[tx*4 + j][k];
      #pragma unroll
      for (int i = 0; i < 4; i++)
        #pragma unroll
        for (int j = 0; j < 4; j++)
          acc[i][j] = fmaf(ra[i], rb[j], acc[i][j]);
    }
  }
  #pragma unroll
  for (int i = 0; i < 4; i++)
    #pragma unroll
    for (int j = 0; j < 4; j++)
      y[(n0 + ty*4 + i) * C_ + k0 + tx*4 + j] = acc[i][j];
}

// ------- resp[n,e]: softmax_e((2(X_n.M_e + cb_e) - cn2_e + gumbel)/tau) --------
__global__ __launch_bounds__(64) void k_resp(const float* __restrict__ x,
    const float* __restrict__ u, const float* __restrict__ M,
    const float* __restrict__ cn2, const float* __restrict__ cb,
    float* __restrict__ resp) {
  int n = blockIdx.x;
  int e = threadIdx.x;
  __shared__ float xs[256];
  *(float4*)&xs[e * 4] = *(const float4*)&x[n * C_ + e * 4];
  __syncthreads();
  const float* Me = M + e * C_;
  float s = 0.f;
  #pragma unroll 8
  for (int j = 0; j < 256; j += 4) {
    float4 m4 = *(const float4*)&Me[j];
    s = fmaf(xs[j],   m4.x, s);
    s = fmaf(xs[j+1], m4.y, s);
    s = fmaf(xs[j+2], m4.z, s);
    s = fmaf(xs[j+3], m4.w, s);
  }
  float uu = u[n * NE + e];
  float g = -logf(-logf(uu));
  float logit = 2.0f * (s + cb[e]) - cn2[e] + g;   // TAU == 1
  float m = logit;
  for (int off = 32; off > 0; off >>= 1) m = fmaxf(m, __shfl_xor(m, off));
  float ex = expf(logit - m);
  float sum = ex;
  for (int off = 32; off > 0; off >>= 1) sum += __shfl_xor(sum, off);
  resp[n * NE + e] = ex / sum;
}

// ---------------- token routing lists per expert ----------------
__global__ __launch_bounds__(256) void k_route(const float* __restrict__ resp,
    unsigned int* __restrict__ cnt, int* __restrict__ tokidx, float* __restrict__ tokr) {
  int t = threadIdx.x;
  int n = blockIdx.x * 64 + (t >> 2);
  int e0 = (t & 3) * 16;
  for (int k = 0; k < 16; k++) {
    int e = e0 + k;
    float r = resp[n * NE + e];
    if (r > RTHRESH) {
      unsigned pos = atomicAdd(&cnt[e], 1u);
      tokidx[e * 2048 + pos] = n;
      tokr[e * 2048 + pos] = r;
    }
  }
}

// ---------------- A = resp^T X, sumresp ----------------
__global__ __launch_bounds__(256) void k_A(const float* __restrict__ resp,
    const float* __restrict__ x, float* __restrict__ A, float* __restrict__ sumresp) {
  int n0 = blockIdx.x * 64;
  __shared__ float rs[64][65];
  __shared__ float xsh[64][257];
  int t = threadIdx.x;
  for (int i = t; i < 4096; i += 256) rs[i >> 6][i & 63] = resp[n0 * NE + i];
  for (int i = t; i < 16384; i += 256) xsh[i >> 8][i & 255] = x[n0 * C_ + i];
  __syncthreads();
  int e = t & 63, q = t >> 6;
  float acc[64];
  #pragma unroll
  for (int cc = 0; cc < 64; cc++) acc[cc] = 0.f;
  float sr = 0.f;
  for (int nn = 0; nn < 64; nn++) {
    float r = rs[nn][e];
    sr += r;
    const float* xr = &xsh[nn][q * 64];
    #pragma unroll
    for (int cc = 0; cc < 64; cc++) acc[cc] = fmaf(r, xr[cc], acc[cc]);
  }
  #pragma unroll
  for (int cc = 0; cc < 64; cc++) atomicAdd(&A[e * C_ + q * 64 + cc], acc[cc]);
  if (q == 0) atomicAdd(&sumresp[e], sr);
}

// ---------------- RR = resp^T resp ----------------
__global__ __launch_bounds__(256) void k_RR(const float* __restrict__ resp, float* __restrict__ RR) {
  int n0 = blockIdx.x * 64;
  __shared__ float rs[64][65];
  int t = threadIdx.x;
  for (int i = t; i < 4096; i += 256) rs[i >> 6][i & 63] = resp[n0 * NE + i];
  __syncthreads();
  int tx = t & 15, ty = t >> 4;
  float acc[4][4] = {};
  for (int nn = 0; nn < 64; nn++) {
    float a_[4], b_[4];
    #pragma unroll
    for (int i = 0; i < 4; i++) a_[i] = rs[nn][ty*4 + i];
    #pragma unroll
    for (int j = 0; j < 4; j++) b_[j] = rs[nn][tx*4 + j];
    #pragma unroll
    for (int i = 0; i < 4; i++)
      #pragma unroll
      for (int j = 0; j < 4; j++)
        acc[i][j] = fmaf(a_[i], b_[j], acc[i][j]);
  }
  #pragma unroll
  for (int i = 0; i < 4; i++)
    #pragma unroll
    for (int j = 0; j < 4; j++)
      atomicAdd(&RR[(ty*4 + i) * NE + tx*4 + j], acc[i][j]);
}

// ------- cnew[e,d] = decay*c + alpha*(A_e.W_d + sumresp_e*b_d) -------
__global__ __launch_bounds__(256) void k_cnew(const float* __restrict__ A,
    const float* __restrict__ sumresp, const float* __restrict__ cen,
    const float* __restrict__ bmap, const float* __restrict__ W,
    float* __restrict__ cnew) {
  int d0 = blockIdx.x * 64;
  __shared__ float As[64][260];
  __shared__ float Ws[64][17];
  int t = threadIdx.x;
  for (int i = t; i < 16384; i += 256) As[i >> 8][i & 255] = A[i];
  int tx = t & 15, ty = t >> 4;
  int dd = t >> 2, k4 = (t & 3) * 4;
  float acc[4][4] = {};
  for (int c0 = 0; c0 < 256; c0 += 16) {
    float4 w4 = *(const float4*)&W[(size_t)(d0 + dd) * C_ + c0 + k4];
    __syncthreads();
    Ws[dd][k4] = w4.x; Ws[dd][k4+1] = w4.y; Ws[dd][k4+2] = w4.z; Ws[dd][k4+3] = w4.w;
    __syncthreads();
    #pragma unroll
    for (int k = 0; k < 16; k++) {
      float ra[4], rb[4];
      #pragma unroll
      for (int i = 0; i < 4; i++) ra[i] = As[ty*4 + i][c0 + k];
      #pragma unroll
      for (int j = 0; j < 4; j++) rb[j] = Ws[tx*4 + j][k];
      #pragma unroll
      for (int i = 0; i < 4; i++)
        #pragma unroll
        for (int j = 0; j < 4; j++)
          acc[i][j] = fmaf(ra[i], rb[j], acc[i][j]);
    }
  }
  #pragma unroll
  for (int i = 0; i < 4; i++) {
    int e = ty*4 + i;
    float sr = sumresp[e];
    #pragma unroll
    for (int j = 0; j < 4; j++) {
      int d = d0 + tx*4 + j;
      cnew[(size_t)e * D_ + d] = DECAYF * cen[(size_t)e * D_ + d]
                               + ALPHA * (acc[i][j] + sr * bmap[d]);
    }
  }
}

// ---------------- CCn = cnew cnew^T ----------------
__global__ __launch_bounds__(256) void k_CC(const float* __restrict__ cnew, float* __restrict__ CCn) {
  int d0 = blockIdx.x * 512;
  __shared__ float cs[64][17];
  int t = threadIdx.x;
  int tx = t & 15, ty = t >> 4;
  int ea = t >> 2, k4 = (t & 3) * 4;
  float acc[4][4] = {};
  for (int dk = 0; dk < 512; dk += 16) {
    float4 v = *(const float4*)&cnew[(size_t)ea * D_ + d0 + dk + k4];
    __syncthreads();
    cs[ea][k4] = v.x; cs[ea][k4+1] = v.y; cs[ea][k4+2] = v.z; cs[ea][k4+3] = v.w;
    __syncthreads();
    #pragma unroll
    for (int k = 0; k < 16; k++) {
      float a_[4], b_[4];
      #pragma unroll
      for (int i = 0; i < 4; i++) a_[i] = cs[ty*4 + i][k];
      #pragma unroll
      for (int j = 0; j < 4; j++) b_[j] = cs[tx*4 + j][k];
      #pragma unroll
      for (int i = 0; i < 4; i++)
        #pragma unroll
        for (int j = 0; j < 4; j++)
          acc[i][j] = fmaf(a_[i], b_[j], acc[i][j]);
    }
  }
  #pragma unroll
  for (int i = 0; i < 4; i++)
    #pragma unroll
    for (int j = 0; j < 4; j++)
      atomicAdd(&CCn[(ty*4 + i) * NE + tx*4 + j], acc[i][j]);
}

// ---------------- cbnew[e] = cnew_e . b (skip if b == 0) ----------------
__global__ __launch_bounds__(256) void k_cbnew(const float* __restrict__ cnew,
    const float* __restrict__ bmap, const float* __restrict__ bb, float* __restrict__ cbnew) {
  if (bb[0] == 0.f) return;   // b identically zero -> cbnew stays zero (pre-zeroed)
  int e = blockIdx.x;
  float s = 0.f;
  for (int d = threadIdx.x; d < D_; d += 256) s = fmaf(cnew[(size_t)e * D_ + d], bmap[d], s);
  __shared__ float red[256];
  red[threadIdx.x] = s;
  __syncthreads();
  for (int k = 128; k > 0; k >>= 1) {
    if (threadIdx.x < k) red[threadIdx.x] += red[threadIdx.x + k];
    __syncthreads();
  }
  if (threadIdx.x == 0) cbnew[e] = red[0];
}

// ---------------- out init with bias ----------------
__global__ __launch_bounds__(256) void k_bias(const float* __restrict__ pwB, float* __restrict__ out) {
  int idx = blockIdx.x * 256 + threadIdx.x;
  out[idx] = pwB[idx & 255];
}

// ------- out[n,i] += r * sum_k cnew[e, i*256+k] * y[n,k] over routed tokens -------
__global__ __launch_bounds__(256) void k_out2(const unsigned int* __restrict__ cnt,
    const int* __restrict__ tokidx, const float* __restrict__ tokr,
    const float* __restrict__ y, const float* __restrict__ cnew,
    float* __restrict__ out) {
  int e = blockIdx.z;
  int base = blockIdx.x * 64;
  int c = (int)cnt[e];
  if (base >= c) return;
  int i0 = blockIdx.y * 64;
  int ntok = min(64, c - base);
  __shared__ int nsh[64];
  __shared__ float rsh[64];
  __shared__ float ys[32][65], cs[32][65];
  int t = threadIdx.x;
  if (t < 64) {
    if (t < ntok) { nsh[t] = tokidx[e * 2048 + base + t]; rsh[t] = tokr[e * 2048 + base + t]; }
    else          { nsh[t] = 0; rsh[t] = 0.f; }
  }
  __syncthreads();
  int tx = t & 15, ty = t >> 4;
  int tok = t >> 2, kb8 = (t & 3) * 8;
  int nrow = nsh[tok];
  float acc[4][4] = {};
  for (int k0 = 0; k0 < 256; k0 += 32) {
    float4 ya = *(const float4*)&y[nrow * C_ + k0 + kb8];
    float4 yb = *(const float4*)&y[nrow * C_ + k0 + kb8 + 4];
    float4 ca = *(const float4*)&cnew[(size_t)e * D_ + (i0 + tok) * C_ + k0 + kb8];
    float4 cb4 = *(const float4*)&cnew[(size_t)e * D_ + (i0 + tok) * C_ + k0 + kb8 + 4];
    __syncthreads();
    ys[kb8+0][tok] = ya.x; ys[kb8+1][tok] = ya.y; ys[kb8+2][tok] = ya.z; ys[kb8+3][tok] = ya.w;
    ys[kb8+4][tok] = yb.x; ys[kb8+5][tok] = yb.y; ys[kb8+6][tok] = yb.z; ys[kb8+7][tok] = yb.w;
    cs[kb8+0][tok] = ca.x; cs[kb8+1][tok] = ca.y; cs[kb8+2][tok] = ca.z; cs[kb8+3][tok] = ca.w;
    cs[kb8+4][tok] = cb4.x; cs[kb8+5][tok] = cb4.y; cs[kb8+6][tok] = cb4.z; cs[kb8+7][tok] = cb4.w;
    __syncthreads();
    #pragma unroll
    for (int kk = 0; kk < 32; kk++) {
      float a_[4], b_[4];
      #pragma unroll
      for (int i = 0; i < 4; i++) a_[i] = ys[kk][ty*4 + i];
      #pragma unroll
      for (int j = 0; j < 4; j++) b_[j] = cs[kk][tx*4 + j];
      #pragma unroll
      for (int i = 0; i < 4; i++)
        #pragma unroll
        for (int j = 0; j < 4; j++)
          acc[i][j] = fmaf(a_[i], b_[j], acc[i][j]);
    }
  }
  #pragma unroll
  for (int i = 0; i < 4; i++) {
    int tk = ty*4 + i;
    float r = rsh[tk];
    if (r == 0.f) continue;
    int n = nsh[tk];
    #pragma unroll
    for (int j = 0; j < 4; j++)
      atomicAdd(&out[n * C_ + i0 + tx*4 + j], r * acc[i][j]);
  }
}

// ---------------- loss assembly ----------------
__global__ __launch_bounds__(256) void k_finalize(
    const float* __restrict__ S, const float* __restrict__ G,
    const float* __restrict__ Mnew, const float* __restrict__ A,
    const float* __restrict__ CCn, const float* __restrict__ RR,
    const float* __restrict__ Xsum, const float* __restrict__ Wb,
    const float* __restrict__ bb, const float* __restrict__ sumresp,
    const float* __restrict__ cbnew, float* __restrict__ out) {
  int t = threadIdx.x;
  float p1 = 0.f, p2 = 0.f, p3 = 0.f, p4 = 0.f, p5 = 0.f;
  for (int i = t; i < 65536; i += 256) p1 = fmaf(G[i], S[i], p1);
  // G block (1,0) was not computed; by symmetry add block (0,1) once more
  for (int i = t; i < 16384; i += 256) {
    int c1 = i >> 7, c2 = 128 + (i & 127);
    p1 = fmaf(G[c1 * C_ + c2], S[c1 * C_ + c2], p1);
  }
  for (int i = t; i < 16384; i += 256) p2 = fmaf(Mnew[i], A[i], p2);
  for (int i = t; i < 4096; i += 256) p3 = fmaf(CCn[i], RR[i], p3);
  p4 = Xsum[t] * Wb[t];
  if (t < 64) p5 = sumresp[t] * cbnew[t];
  __shared__ float red[5][256];
  red[0][t] = p1; red[1][t] = p2; red[2][t] = p3; red[3][t] = p4; red[4][t] = p5;
  __syncthreads();
  for (int s = 128; s > 0; s >>= 1) {
    if (t < s) {
      #pragma unroll
      for (int q = 0; q < 5; q++) red[q][t] += red[q][t + s];
    }
    __syncthreads();
  }
  if (t == 0) {
    float sumkeyf2 = red[0][0] + 2.0f * red[3][0] + 2048.0f * bb[0];
    float cross    = red[1][0] + red[4][0];
    float sumq2    = red[2][0];
    float loss = (0.25f / (2048.0f * 65536.0f)) * (sumkeyf2 - 2.0f * cross + sumq2);
    out[524288] = loss;
  }
}

extern "C" void kernel_launch(void* const* d_in, const int* in_sizes, int n_in,
                              void* d_out, int out_size, void* d_ws, size_t ws_size,
                              hipStream_t stream) {
  const float* x    = (const float*)d_in[0];
  const float* u    = (const float*)d_in[1];
  const float* Wm   = (const float*)d_in[2];
  const float* bmap = (const float*)d_in[3];
  const float* pw   = (const float*)d_in[4];
  const float* pwB  = (const float*)d_in[5];
  const float* cen  = (const float*)d_in[6];
  float* out = (float*)d_out;
  float* ws  = (float*)d_ws;

  float* S_      = ws + OFF_S;
  float* Xsum    = ws + OFF_XSUM;
  float* G       = ws + OFF_G;
  float* M       = ws + OFF_M;
  float* Wb      = ws + OFF_WB;
  float* bb      = ws + OFF_BB;
  float* sumresp = ws + OFF_SUMR;
  float* A       = ws + OFF_A;
  float* Mnew    = ws + OFF_MNEW;
  float* CCn     = ws + OFF_CCN;
  float* RR      = ws + OFF_RR;
  float* cbnew   = ws + OFF_CBNEW;
  unsigned int* cnt = (unsigned int*)(ws + OFF_CNT);
  float* cn2     = ws + OFF_CN2;
  float* cb      = ws + OFF_CB;
  float* resp    = ws + OFF_RESP;
  float* y       = ws + OFF_Y;
  float* cnew    = ws + OFF_CNEW;
  int*   tokidx  = (int*)(ws + OFF_TIDX);
  float* tokr    = ws + OFF_TOKR;

  hipMemsetAsync(d_ws, 0, ZFLOATS * sizeof(float), stream);

  k_cstats<<<64, 256, 0, stream>>>(cen, bmap, cn2, cb);
  k_bb<<<1, 256, 0, stream>>>(bmap, bb);
  k_S<<<dim3(8, 8), 256, 0, stream>>>(x, S_);
  k_xsum<<<32, 256, 0, stream>>>(x, Xsum);
  k_G<<<dim3(64, 3), 256, 0, stream>>>(Wm, G);
  k_mm64<<<dim3(64, 4), 256, 0, stream>>>(cen, Wm, M);
  k_Wb<<<256, 256, 0, stream>>>(bmap, Wm, Wb);
  k_y<<<dim3(32, 4), 256, 0, stream>>>(x, pw, y);
  k_resp<<<2048, 64, 0, stream>>>(x, u, M, cn2, cb, resp);
  k_route<<<32, 256, 0, stream>>>(resp, cnt, tokidx, tokr);
  k_A<<<32, 256, 0, stream>>>(resp, x, A, sumresp);
  k_RR<<<32, 256, 0, stream>>>(resp, RR);
  k_cnew<<<1024, 256, 0, stream>>>(A, sumresp, cen, bmap, Wm, cnew);
  k_mm64<<<dim3(64, 4), 256, 0, stream>>>(cnew, Wm, Mnew);
  k_CC<<<128, 256, 0, stream>>>(cnew, CCn);
  k_cbnew<<<64, 256, 0, stream>>>(cnew, bmap, bb, cbnew);
  k_bias<<<2048, 256, 0, stream>>>(pwB, out);
  k_out2<<<dim3(32, 4, 64), 256, 0, stream>>>(cnt, tokidx, tokr, y, cnew, out);
  k_finalize<<<1, 256, 0, stream>>>(S_, G, Mnew, A, CCn, RR, Xsum, Wb, bb,
                                    sumresp, cbnew, out);
}

// Round 2
// 1110.532 us; speedup vs baseline: 1.1260x; 1.1260x over previous
//
#include <hip/hip_runtime.h>

// Problem dims
constexpr int N_TOK = 2048;   // T*B
constexpr int C_    = 256;    // in features (== R == OUT)
constexpr int NE    = 64;     // experts
constexpr int D_    = 65536;  // R*OUT centroid dim
constexpr float DECAYF = 0.999f;
constexpr float OMD    = 0.001f;          // f32(1.0 - 0.999) as jnp uses
constexpr float ALPHA  = OMD / 2048.0f;   // (1-decay)/N
constexpr float RTHRESH = 1e-5f;          // routing weight cutoff (err <= 64*1e-5*|O| << 0.8)

// ---------- workspace layout (float offsets) ----------
// zero-initialized zone (atomically accumulated or conditionally written):
constexpr size_t OFF_S     = 0;        // 65536  S = X^T X (full)
constexpr size_t OFF_XSUM  = 65536;    // 256
constexpr size_t OFF_G     = 65792;    // 65536  G = W^T W (upper-tri 64x64 tile pairs only)
constexpr size_t OFF_M     = 131328;   // 16384  M = c @ W
constexpr size_t OFF_WB    = 147712;   // 256    Wb = b^T W
constexpr size_t OFF_BB    = 147968;   // 16     bb = ||b||^2
constexpr size_t OFF_SUMR  = 147984;   // 64     sum_n resp
constexpr size_t OFF_A     = 148048;   // 16384  A = resp^T X
constexpr size_t OFF_MNEW  = 164432;   // 16384  Mnew = cnew @ W
constexpr size_t OFF_CCN   = 180816;   // 4096   cnew cnew^T
constexpr size_t OFF_RR    = 184912;   // 4096   resp^T resp
constexpr size_t OFF_CBNEW = 189008;   // 64     cnew . b
constexpr size_t OFF_CNT   = 189072;   // 64     per-expert token counts (uint)
constexpr size_t OFF_CN2   = 189136;   // 64     ||c_e||^2
constexpr size_t OFF_CB    = 189200;   // 64     c_e . b
constexpr size_t ZFLOATS   = 189264;
// overwritten-before-read zone:
constexpr size_t OFF_RESP  = 189264;   // 131072
constexpr size_t OFF_Y     = 320336;   // 524288 y = X @ pw^T
constexpr size_t OFF_CNEW  = 844624;   // 4194304
constexpr size_t OFF_TIDX  = 5038928;  // 131072 (int) token lists
constexpr size_t OFF_TOKR  = 5170000;  // 131072 token resp values

// ------- centroid stats: cn2[e], cb[e] (d-split x4 for occupancy) -------
__global__ __launch_bounds__(256) void k_cstats(const float* __restrict__ cen,
    const float* __restrict__ bmap, float* __restrict__ cn2, float* __restrict__ cb) {
  int e = blockIdx.x >> 2;
  int d0 = (blockIdx.x & 3) * 16384;
  const float* ce = cen + (size_t)e * D_ + d0;
  const float* bm = bmap + d0;
  float s2 = 0.f, sb = 0.f;
  for (int d = threadIdx.x; d < 16384; d += 256) {
    float v = ce[d];
    s2 = fmaf(v, v, s2);
    sb = fmaf(v, bm[d], sb);
  }
  __shared__ float r0[256], r1[256];
  r0[threadIdx.x] = s2; r1[threadIdx.x] = sb;
  __syncthreads();
  for (int s = 128; s > 0; s >>= 1) {
    if (threadIdx.x < s) { r0[threadIdx.x] += r0[threadIdx.x + s];
                           r1[threadIdx.x] += r1[threadIdx.x + s]; }
    __syncthreads();
  }
  if (threadIdx.x == 0) { atomicAdd(&cn2[e], r0[0]); atomicAdd(&cb[e], r1[0]); }
}

// ---------------- bb = ||b||^2 ----------------
__global__ __launch_bounds__(256) void k_bb(const float* __restrict__ bmap, float* __restrict__ bb) {
  float s = 0.f;
  for (int d = threadIdx.x; d < D_; d += 256) { float v = bmap[d]; s = fmaf(v, v, s); }
  __shared__ float red[256];
  red[threadIdx.x] = s;
  __syncthreads();
  for (int k = 128; k > 0; k >>= 1) {
    if (threadIdx.x < k) red[threadIdx.x] += red[threadIdx.x + k];
    __syncthreads();
  }
  if (threadIdx.x == 0) bb[0] = red[0];
}

// ======== shared pattern: 64x64 tile of A^T A over a k-chunk, atomics out =======
// Used by k_S (A=x, K=2048) and k_G (A=W, K=65536).
// ra reads are 4-distinct-float4 broadcast (conflict-free);
// rb reads are 16 float4 stride-16B -> 2-way (free per m136).
template<int KCHUNK>
__device__ __forceinline__ void gram_tile(const float* __restrict__ Wsrc,
    int d0, int c1, int c2, float* __restrict__ Out, int ldo) {
  __shared__ float Wa[32][68], Wb[32][68];
  int t = threadIdx.x;
  int tx = t & 15, ty = t >> 4;       // 16x16 thread grid, 4x4 per thread
  int lr = t >> 3, lc = (t & 7) * 8;  // load map: 32 rows x 64 cols per tile
  float acc[4][4] = {};
  for (int dk = 0; dk < KCHUNK; dk += 32) {
    const float* Wrow = &Wsrc[(size_t)(d0 + dk + lr) * C_];
    float4 a0 = *(const float4*)&Wrow[c1 + lc];
    float4 a1 = *(const float4*)&Wrow[c1 + lc + 4];
    float4 b0 = *(const float4*)&Wrow[c2 + lc];
    float4 b1 = *(const float4*)&Wrow[c2 + lc + 4];
    __syncthreads();
    *(float4*)&Wa[lr][lc]     = a0;
    *(float4*)&Wa[lr][lc + 4] = a1;
    *(float4*)&Wb[lr][lc]     = b0;
    *(float4*)&Wb[lr][lc + 4] = b1;
    __syncthreads();
    #pragma unroll
    for (int k = 0; k < 32; k++) {
      float4 ra4 = *(const float4*)&Wa[k][ty * 4];
      float4 rb4 = *(const float4*)&Wb[k][tx * 4];
      float ra[4] = {ra4.x, ra4.y, ra4.z, ra4.w};
      float rb[4] = {rb4.x, rb4.y, rb4.z, rb4.w};
      #pragma unroll
      for (int i = 0; i < 4; i++)
        #pragma unroll
        for (int j = 0; j < 4; j++)
          acc[i][j] = fmaf(ra[i], rb[j], acc[i][j]);
    }
  }
  #pragma unroll
  for (int i = 0; i < 4; i++)
    #pragma unroll
    for (int j = 0; j < 4; j++)
      atomicAdd(&Out[(c1 + ty * 4 + i) * ldo + c2 + tx * 4 + j], acc[i][j]);
}

// ---- G = W^T W: upper-tri 64x64 tile pairs (10), ksplit 64x1024 -> 640 blocks ----
__global__ __launch_bounds__(256) void k_G(const float* __restrict__ W, float* __restrict__ G) {
  int p = blockIdx.y;
  // p -> (ti,tj), ti<=tj, in 0..3
  int ti = 0, rem = p;
  while (rem >= 4 - ti) { rem -= 4 - ti; ti++; }
  int tj = ti + rem;
  gram_tile<1024>(W, blockIdx.x * 1024, ti * 64, tj * 64, G, C_);
}

// ---- S = X^T X: full 16 tile pairs, ksplit 8x256 -> 128 blocks ----
__global__ __launch_bounds__(256) void k_S(const float* __restrict__ x, float* __restrict__ S) {
  int p = blockIdx.y;
  int ti = p >> 2, tj = p & 3;
  gram_tile<256>(x, blockIdx.x * 256, ti * 64, tj * 64, S, C_);
}

// ---------------- Xsum[c] = sum_n X[n,c] ----------------
__global__ __launch_bounds__(256) void k_xsum(const float* __restrict__ x, float* __restrict__ xsum) {
  int n0 = blockIdx.x * 64;
  int c = threadIdx.x;
  float s = 0.f;
  for (int n = 0; n < 64; n++) s += x[(n0 + n) * C_ + c];
  atomicAdd(&xsum[c], s);
}

// -------- Out[64,256] += Arows[64,D] @ W[D,256]  (M and Mnew), ksplit 128x512 ----
__global__ __launch_bounds__(256) void k_mm64(const float* __restrict__ Arows,
    const float* __restrict__ W, float* __restrict__ Out) {
  int d0 = blockIdx.x * 512;
  int c0 = blockIdx.y * 64;
  __shared__ float As[64][17];
  __shared__ float Bs[16][68];
  int t = threadIdx.x;
  int tx = t & 15, ty = t >> 4;
  int ea = t >> 2, k4 = (t & 3) * 4;
  int kb = t >> 4, cc4 = (t & 15) * 4;
  float acc[4][4] = {};
  for (int dk = 0; dk < 512; dk += 16) {
    float4 va = *(const float4*)&Arows[(size_t)ea * D_ + d0 + dk + k4];
    float4 vb = *(const float4*)&W[(size_t)(d0 + dk + kb) * C_ + c0 + cc4];
    __syncthreads();
    As[ea][k4] = va.x; As[ea][k4+1] = va.y; As[ea][k4+2] = va.z; As[ea][k4+3] = va.w;
    *(float4*)&Bs[kb][cc4] = vb;
    __syncthreads();
    #pragma unroll
    for (int k = 0; k < 16; k++) {
      float ra[4], rb[4];
      #pragma unroll
      for (int i = 0; i < 4; i++) ra[i] = As[ty*4 + i][k];
      #pragma unroll
      for (int j = 0; j < 4; j++) rb[j] = Bs[k][tx*4 + j];
      #pragma unroll
      for (int i = 0; i < 4; i++)
        #pragma unroll
        for (int j = 0; j < 4; j++)
          acc[i][j] = fmaf(ra[i], rb[j], acc[i][j]);
    }
  }
  #pragma unroll
  for (int i = 0; i < 4; i++)
    #pragma unroll
    for (int j = 0; j < 4; j++)
      atomicAdd(&Out[(ty*4 + i) * C_ + c0 + tx*4 + j], acc[i][j]);
}

// ---------------- Wb[c] = sum_d b[d] W[d,c] (skips all-zero b chunks) ----------
__global__ __launch_bounds__(256) void k_Wb(const float* __restrict__ bmap,
    const float* __restrict__ W, float* __restrict__ Wb) {
  int d0 = blockIdx.x * 256;
  int c = threadIdx.x;
  __shared__ float bs[256];
  __shared__ int any;
  if (c == 0) any = 0;
  __syncthreads();
  float bv = bmap[d0 + c];
  bs[c] = bv;
  if (bv != 0.f) any = 1;
  __syncthreads();
  if (any == 0) return;
  float s = 0.f;
  for (int d = 0; d < 256; d++) s = fmaf(bs[d], W[(size_t)(d0 + d) * C_ + c], s);
  atomicAdd(&Wb[c], s);
}

// ---------------- y[n,k] = sum_j X[n,j] pw[k,j] ----------------
__global__ __launch_bounds__(256) void k_y(const float* __restrict__ x,
    const float* __restrict__ pw, float* __restrict__ y) {
  int n0 = blockIdx.x * 64, k0 = blockIdx.y * 64;
  __shared__ float Xs[64][17], Ps[64][17];
  int t = threadIdx.x;
  int tx = t & 15, ty = t >> 4;
  int r = t >> 2, q4 = (t & 3) * 4;
  float acc[4][4] = {};
  for (int j0 = 0; j0 < 256; j0 += 16) {
    float4 va = *(const float4*)&x[(n0 + r) * C_ + j0 + q4];
    float4 vb = *(const float4*)&pw[(k0 + r) * C_ + j0 + q4];
    __syncthreads();
    Xs[r][q4] = va.x; Xs[r][q4+1] = va.y; Xs[r][q4+2] = va.z; Xs[r][q4+3] = va.w;
    Ps[r][q4] = vb.x; Ps[r][q4+1] = vb.y; Ps[r][q4+2] = vb.z; Ps[r][q4+3] = vb.w;
    __syncthreads();
    #pragma unroll
    for (int k = 0; k < 16; k++) {
      float ra[4], rb[4];
      #pragma unroll
      for (int i = 0; i < 4; i++) ra[i] = Xs[ty*4 + i][k];
      #pragma unroll
      for (int j = 0; j < 4; j++) rb[j] = Ps[tx*4 + j][k];
      #pragma unroll
      for (int i = 0; i < 4; i++)
        #pragma unroll
        for (int j = 0; j < 4; j++)
          acc[i][j] = fmaf(ra[i], rb[j], acc[i][j]);
    }
  }
  #pragma unroll
  for (int i = 0; i < 4; i++)
    #pragma unroll
    for (int j = 0; j < 4; j++)
      y[(n0 + ty*4 + i) * C_ + k0 + tx*4 + j] = acc[i][j];
}

// ------- resp[n,e]: softmax_e((2(X_n.M_e + cb_e) - cn2_e + gumbel)/tau) --------
__global__ __launch_bounds__(64) void k_resp(const float* __restrict__ x,
    const float* __restrict__ u, const float* __restrict__ M,
    const float* __restrict__ cn2, const float* __restrict__ cb,
    float* __restrict__ resp) {
  int n = blockIdx.x;
  int e = threadIdx.x;
  __shared__ float xs[256];
  *(float4*)&xs[e * 4] = *(const float4*)&x[n * C_ + e * 4];
  __syncthreads();
  const float* Me = M + e * C_;
  float s = 0.f;
  #pragma unroll 8
  for (int j = 0; j < 256; j += 4) {
    float4 m4 = *(const float4*)&Me[j];
    s = fmaf(xs[j],   m4.x, s);
    s = fmaf(xs[j+1], m4.y, s);
    s = fmaf(xs[j+2], m4.z, s);
    s = fmaf(xs[j+3], m4.w, s);
  }
  float uu = u[n * NE + e];
  float g = -logf(-logf(uu));
  float logit = 2.0f * (s + cb[e]) - cn2[e] + g;   // TAU == 1
  float m = logit;
  for (int off = 32; off > 0; off >>= 1) m = fmaxf(m, __shfl_xor(m, off));
  float ex = expf(logit - m);
  float sum = ex;
  for (int off = 32; off > 0; off >>= 1) sum += __shfl_xor(sum, off);
  resp[n * NE + e] = ex / sum;
}

// ---------------- token routing lists per expert ----------------
__global__ __launch_bounds__(256) void k_route(const float* __restrict__ resp,
    unsigned int* __restrict__ cnt, int* __restrict__ tokidx, float* __restrict__ tokr) {
  int t = threadIdx.x;
  int n = blockIdx.x * 64 + (t >> 2);
  int e0 = (t & 3) * 16;
  for (int k = 0; k < 16; k++) {
    int e = e0 + k;
    float r = resp[n * NE + e];
    if (r > RTHRESH) {
      unsigned pos = atomicAdd(&cnt[e], 1u);
      tokidx[e * 2048 + pos] = n;
      tokr[e * 2048 + pos] = r;
    }
  }
}

// ---------------- A = resp^T X, sumresp  (n-chunks of 16 -> 128 blocks) --------
__global__ __launch_bounds__(256) void k_A(const float* __restrict__ resp,
    const float* __restrict__ x, float* __restrict__ A, float* __restrict__ sumresp) {
  int n0 = blockIdx.x * 16;
  __shared__ float rs[16][65];
  __shared__ float xsh[16][257];
  int t = threadIdx.x;
  for (int i = t; i < 1024; i += 256) rs[i >> 6][i & 63] = resp[n0 * NE + i];
  for (int i = t; i < 4096; i += 256) xsh[i >> 8][i & 255] = x[n0 * C_ + i];
  __syncthreads();
  int e = t & 63, q = t >> 6;
  float acc[64];
  #pragma unroll
  for (int cc = 0; cc < 64; cc++) acc[cc] = 0.f;
  float sr = 0.f;
  for (int nn = 0; nn < 16; nn++) {
    float r = rs[nn][e];
    sr += r;
    const float* xr = &xsh[nn][q * 64];
    #pragma unroll
    for (int cc = 0; cc < 64; cc++) acc[cc] = fmaf(r, xr[cc], acc[cc]);
  }
  #pragma unroll
  for (int cc = 0; cc < 64; cc++) atomicAdd(&A[e * C_ + q * 64 + cc], acc[cc]);
  if (q == 0) atomicAdd(&sumresp[e], sr);
}

// ---------------- RR = resp^T resp ----------------
__global__ __launch_bounds__(256) void k_RR(const float* __restrict__ resp, float* __restrict__ RR) {
  int n0 = blockIdx.x * 64;
  __shared__ float rs[64][65];
  int t = threadIdx.x;
  for (int i = t; i < 4096; i += 256) rs[i >> 6][i & 63] = resp[n0 * NE + i];
  __syncthreads();
  int tx = t & 15, ty = t >> 4;
  float acc[4][4] = {};
  for (int nn = 0; nn < 64; nn++) {
    float a_[4], b_[4];
    #pragma unroll
    for (int i = 0; i < 4; i++) a_[i] = rs[nn][ty*4 + i];
    #pragma unroll
    for (int j = 0; j < 4; j++) b_[j] = rs[nn][tx*4 + j];
    #pragma unroll
    for (int i = 0; i < 4; i++)
      #pragma unroll
      for (int j = 0; j < 4; j++)
        acc[i][j] = fmaf(a_[i], b_[j], acc[i][j]);
  }
  #pragma unroll
  for (int i = 0; i < 4; i++)
    #pragma unroll
    for (int j = 0; j < 4; j++)
      atomicAdd(&RR[(ty*4 + i) * NE + tx*4 + j], acc[i][j]);
}

// ------- cnew[e,d] = decay*c + alpha*(A_e.W_d + sumresp_e*b_d) -------
__global__ __launch_bounds__(256) void k_cnew(const float* __restrict__ A,
    const float* __restrict__ sumresp, const float* __restrict__ cen,
    const float* __restrict__ bmap, const float* __restrict__ W,
    float* __restrict__ cnew) {
  int d0 = blockIdx.x * 64;
  __shared__ float As[64][260];
  __shared__ float Ws[64][17];
  int t = threadIdx.x;
  for (int i = t; i < 16384; i += 256) As[i >> 8][i & 255] = A[i];
  int tx = t & 15, ty = t >> 4;
  int dd = t >> 2, k4 = (t & 3) * 4;
  float acc[4][4] = {};
  for (int c0 = 0; c0 < 256; c0 += 16) {
    float4 w4 = *(const float4*)&W[(size_t)(d0 + dd) * C_ + c0 + k4];
    __syncthreads();
    Ws[dd][k4] = w4.x; Ws[dd][k4+1] = w4.y; Ws[dd][k4+2] = w4.z; Ws[dd][k4+3] = w4.w;
    __syncthreads();
    #pragma unroll
    for (int k = 0; k < 16; k++) {
      float ra[4], rb[4];
      #pragma unroll
      for (int i = 0; i < 4; i++) ra[i] = As[ty*4 + i][c0 + k];
      #pragma unroll
      for (int j = 0; j < 4; j++) rb[j] = Ws[tx*4 + j][k];
      #pragma unroll
      for (int i = 0; i < 4; i++)
        #pragma unroll
        for (int j = 0; j < 4; j++)
          acc[i][j] = fmaf(ra[i], rb[j], acc[i][j]);
    }
  }
  #pragma unroll
  for (int i = 0; i < 4; i++) {
    int e = ty*4 + i;
    float sr = sumresp[e];
    #pragma unroll
    for (int j = 0; j < 4; j++) {
      int d = d0 + tx*4 + j;
      cnew[(size_t)e * D_ + d] = DECAYF * cen[(size_t)e * D_ + d]
                               + ALPHA * (acc[i][j] + sr * bmap[d]);
    }
  }
}

// ---------------- CCn = cnew cnew^T ----------------
__global__ __launch_bounds__(256) void k_CC(const float* __restrict__ cnew, float* __restrict__ CCn) {
  int d0 = blockIdx.x * 512;
  __shared__ float cs[64][17];
  int t = threadIdx.x;
  int tx = t & 15, ty = t >> 4;
  int ea = t >> 2, k4 = (t & 3) * 4;
  float acc[4][4] = {};
  for (int dk = 0; dk < 512; dk += 16) {
    float4 v = *(const float4*)&cnew[(size_t)ea * D_ + d0 + dk + k4];
    __syncthreads();
    cs[ea][k4] = v.x; cs[ea][k4+1] = v.y; cs[ea][k4+2] = v.z; cs[ea][k4+3] = v.w;
    __syncthreads();
    #pragma unroll
    for (int k = 0; k < 16; k++) {
      float a_[4], b_[4];
      #pragma unroll
      for (int i = 0; i < 4; i++) a_[i] = cs[ty*4 + i][k];
      #pragma unroll
      for (int j = 0; j < 4; j++) b_[j] = cs[tx*4 + j][k];
      #pragma unroll
      for (int i = 0; i < 4; i++)
        #pragma unroll
        for (int j = 0; j < 4; j++)
          acc[i][j] = fmaf(a_[i], b_[j], acc[i][j]);
    }
  }
  #pragma unroll
  for (int i = 0; i < 4; i++)
    #pragma unroll
    for (int j = 0; j < 4; j++)
      atomicAdd(&CCn[(ty*4 + i) * NE + tx*4 + j], acc[i][j]);
}

// ---------------- cbnew[e] = cnew_e . b (skip if b == 0) ----------------
__global__ __launch_bounds__(256) void k_cbnew(const float* __restrict__ cnew,
    const float* __restrict__ bmap, const float* __restrict__ bb, float* __restrict__ cbnew) {
  if (bb[0] == 0.f) return;   // b identically zero -> cbnew stays zero (pre-zeroed)
  int e = blockIdx.x;
  float s = 0.f;
  for (int d = threadIdx.x; d < D_; d += 256) s = fmaf(cnew[(size_t)e * D_ + d], bmap[d], s);
  __shared__ float red[256];
  red[threadIdx.x] = s;
  __syncthreads();
  for (int k = 128; k > 0; k >>= 1) {
    if (threadIdx.x < k) red[threadIdx.x] += red[threadIdx.x + k];
    __syncthreads();
  }
  if (threadIdx.x == 0) cbnew[e] = red[0];
}

// ---------------- out init with bias ----------------
__global__ __launch_bounds__(256) void k_bias(const float* __restrict__ pwB, float* __restrict__ out) {
  int idx = blockIdx.x * 256 + threadIdx.x;
  out[idx] = pwB[idx & 255];
}

// ------- out[n,i] += r * sum_k cnew[e, i*256+k] * y[n,k] over routed tokens -------
__global__ __launch_bounds__(256) void k_out2(const unsigned int* __restrict__ cnt,
    const int* __restrict__ tokidx, const float* __restrict__ tokr,
    const float* __restrict__ y, const float* __restrict__ cnew,
    float* __restrict__ out) {
  int e = blockIdx.z;
  int base = blockIdx.x * 64;
  int c = (int)cnt[e];
  if (base >= c) return;
  int i0 = blockIdx.y * 64;
  int ntok = min(64, c - base);
  __shared__ int nsh[64];
  __shared__ float rsh[64];
  __shared__ float ys[32][65], cs[32][65];
  int t = threadIdx.x;
  if (t < 64) {
    if (t < ntok) { nsh[t] = tokidx[e * 2048 + base + t]; rsh[t] = tokr[e * 2048 + base + t]; }
    else          { nsh[t] = 0; rsh[t] = 0.f; }
  }
  __syncthreads();
  int tx = t & 15, ty = t >> 4;
  int tok = t >> 2, kb8 = (t & 3) * 8;
  int nrow = nsh[tok];
  float acc[4][4] = {};
  for (int k0 = 0; k0 < 256; k0 += 32) {
    float4 ya = *(const float4*)&y[nrow * C_ + k0 + kb8];
    float4 yb = *(const float4*)&y[nrow * C_ + k0 + kb8 + 4];
    float4 ca = *(const float4*)&cnew[(size_t)e * D_ + (i0 + tok) * C_ + k0 + kb8];
    float4 cb4 = *(const float4*)&cnew[(size_t)e * D_ + (i0 + tok) * C_ + k0 + kb8 + 4];
    __syncthreads();
    ys[kb8+0][tok] = ya.x; ys[kb8+1][tok] = ya.y; ys[kb8+2][tok] = ya.z; ys[kb8+3][tok] = ya.w;
    ys[kb8+4][tok] = yb.x; ys[kb8+5][tok] = yb.y; ys[kb8+6][tok] = yb.z; ys[kb8+7][tok] = yb.w;
    cs[kb8+0][tok] = ca.x; cs[kb8+1][tok] = ca.y; cs[kb8+2][tok] = ca.z; cs[kb8+3][tok] = ca.w;
    cs[kb8+4][tok] = cb4.x; cs[kb8+5][tok] = cb4.y; cs[kb8+6][tok] = cb4.z; cs[kb8+7][tok] = cb4.w;
    __syncthreads();
    #pragma unroll
    for (int kk = 0; kk < 32; kk++) {
      float a_[4], b_[4];
      #pragma unroll
      for (int i = 0; i < 4; i++) a_[i] = ys[kk][ty*4 + i];
      #pragma unroll
      for (int j = 0; j < 4; j++) b_[j] = cs[kk][tx*4 + j];
      #pragma unroll
      for (int i = 0; i < 4; i++)
        #pragma unroll
        for (int j = 0; j < 4; j++)
          acc[i][j] = fmaf(a_[i], b_[j], acc[i][j]);
    }
  }
  #pragma unroll
  for (int i = 0; i < 4; i++) {
    int tk = ty*4 + i;
    float r = rsh[tk];
    if (r == 0.f) continue;
    int n = nsh[tk];
    #pragma unroll
    for (int j = 0; j < 4; j++)
      atomicAdd(&out[n * C_ + i0 + tx*4 + j], r * acc[i][j]);
  }
}

// ---------------- loss assembly ----------------
// G is stored upper-tri at 64x64 tile granularity; S is full & symmetric, so
// off-diagonal tiles contribute twice.
__global__ __launch_bounds__(256) void k_finalize(
    const float* __restrict__ S, const float* __restrict__ G,
    const float* __restrict__ Mnew, const float* __restrict__ A,
    const float* __restrict__ CCn, const float* __restrict__ RR,
    const float* __restrict__ Xsum, const float* __restrict__ Wb,
    const float* __restrict__ bb, const float* __restrict__ sumresp,
    const float* __restrict__ cbnew, float* __restrict__ out) {
  int t = threadIdx.x;
  float p1 = 0.f, p2 = 0.f, p3 = 0.f, p4 = 0.f, p5 = 0.f;
  for (int i = t; i < 65536; i += 256) {
    int c1 = i >> 8, c2 = i & 255;
    int t1 = c1 >> 6, t2 = c2 >> 6;
    if (t1 > t2) continue;
    float w = (t1 == t2) ? 1.0f : 2.0f;
    p1 = fmaf(w * G[i], S[i], p1);
  }
  for (int i = t; i < 16384; i += 256) p2 = fmaf(Mnew[i], A[i], p2);
  for (int i = t; i < 4096; i += 256) p3 = fmaf(CCn[i], RR[i], p3);
  p4 = Xsum[t] * Wb[t];
  if (t < 64) p5 = sumresp[t] * cbnew[t];
  __shared__ float red[5][256];
  red[0][t] = p1; red[1][t] = p2; red[2][t] = p3; red[3][t] = p4; red[4][t] = p5;
  __syncthreads();
  for (int s = 128; s > 0; s >>= 1) {
    if (t < s) {
      #pragma unroll
      for (int q = 0; q < 5; q++) red[q][t] += red[q][t + s];
    }
    __syncthreads();
  }
  if (t == 0) {
    float sumkeyf2 = red[0][0] + 2.0f * red[3][0] + 2048.0f * bb[0];
    float cross    = red[1][0] + red[4][0];
    float sumq2    = red[2][0];
    float loss = (0.25f / (2048.0f * 65536.0f)) * (sumkeyf2 - 2.0f * cross + sumq2);
    out[524288] = loss;
  }
}

extern "C" void kernel_launch(void* const* d_in, const int* in_sizes, int n_in,
                              void* d_out, int out_size, void* d_ws, size_t ws_size,
                              hipStream_t stream) {
  const float* x    = (const float*)d_in[0];
  const float* u    = (const float*)d_in[1];
  const float* Wm   = (const float*)d_in[2];
  const float* bmap = (const float*)d_in[3];
  const float* pw   = (const float*)d_in[4];
  const float* pwB  = (const float*)d_in[5];
  const float* cen  = (const float*)d_in[6];
  float* out = (float*)d_out;
  float* ws  = (float*)d_ws;

  float* S_      = ws + OFF_S;
  float* Xsum    = ws + OFF_XSUM;
  float* G       = ws + OFF_G;
  float* M       = ws + OFF_M;
  float* Wb      = ws + OFF_WB;
  float* bb      = ws + OFF_BB;
  float* sumresp = ws + OFF_SUMR;
  float* A       = ws + OFF_A;
  float* Mnew    = ws + OFF_MNEW;
  float* CCn     = ws + OFF_CCN;
  float* RR      = ws + OFF_RR;
  float* cbnew   = ws + OFF_CBNEW;
  unsigned int* cnt = (unsigned int*)(ws + OFF_CNT);
  float* cn2     = ws + OFF_CN2;
  float* cb      = ws + OFF_CB;
  float* resp    = ws + OFF_RESP;
  float* y       = ws + OFF_Y;
  float* cnew    = ws + OFF_CNEW;
  int*   tokidx  = (int*)(ws + OFF_TIDX);
  float* tokr    = ws + OFF_TOKR;

  hipMemsetAsync(d_ws, 0, ZFLOATS * sizeof(float), stream);

  k_cstats<<<256, 256, 0, stream>>>(cen, bmap, cn2, cb);
  k_bb<<<1, 256, 0, stream>>>(bmap, bb);
  k_S<<<dim3(8, 16), 256, 0, stream>>>(x, S_);
  k_xsum<<<32, 256, 0, stream>>>(x, Xsum);
  k_G<<<dim3(64, 10), 256, 0, stream>>>(Wm, G);
  k_mm64<<<dim3(128, 4), 256, 0, stream>>>(cen, Wm, M);
  k_Wb<<<256, 256, 0, stream>>>(bmap, Wm, Wb);
  k_y<<<dim3(32, 4), 256, 0, stream>>>(x, pw, y);
  k_resp<<<2048, 64, 0, stream>>>(x, u, M, cn2, cb, resp);
  k_route<<<32, 256, 0, stream>>>(resp, cnt, tokidx, tokr);
  k_A<<<128, 256, 0, stream>>>(resp, x, A, sumresp);
  k_RR<<<32, 256, 0, stream>>>(resp, RR);
  k_cnew<<<1024, 256, 0, stream>>>(A, sumresp, cen, bmap, Wm, cnew);
  k_mm64<<<dim3(128, 4), 256, 0, stream>>>(cnew, Wm, Mnew);
  k_CC<<<128, 256, 0, stream>>>(cnew, CCn);
  k_cbnew<<<64, 256, 0, stream>>>(cnew, bmap, bb, cbnew);
  k_bias<<<2048, 256, 0, stream>>>(pwB, out);
  k_out2<<<dim3(32, 4, 64), 256, 0, stream>>>(cnt, tokidx, tokr, y, cnew, out);
  k_finalize<<<1, 256, 0, stream>>>(S_, G, Mnew, A, CCn, RR, Xsum, Wb, bb,
                                    sumresp, cbnew, out);
}

// Round 4
// 876.776 us; speedup vs baseline: 1.4262x; 1.2666x over previous
//
#include <hip/hip_runtime.h>

// Problem dims
constexpr int N_TOK = 2048;   // T*B
constexpr int C_    = 256;    // in features (== R == OUT)
constexpr int NE    = 64;     // experts
constexpr int D_    = 65536;  // R*OUT centroid dim
constexpr float DECAYF = 0.999f;
constexpr float OMD    = 0.001f;          // f32(1.0 - 0.999) as jnp uses
constexpr float ALPHA  = OMD / 2048.0f;   // (1-decay)/N
constexpr float RTHRESH = 1e-5f;          // routing weight cutoff
constexpr int CHMAX = 8448;               // >= worst-case sum_e ceil(cnt_e/16) = 8256
constexpr int SA_GRIDX = 512;             // k_sA grid-stride width

// ---------- workspace layout (float offsets) ----------
// zero-initialized zone:
constexpr size_t OFF_S     = 0;        // 65536  S = X^T X (full)
constexpr size_t OFF_XSUM  = 65536;    // 256
constexpr size_t OFF_G     = 65792;    // 65536  G = W^T W (triangle, mirrored to full)
constexpr size_t OFF_M     = 131328;   // 16384  M = cen @ W
constexpr size_t OFF_WB    = 147712;   // 256    Wb = b^T W
constexpr size_t OFF_BB    = 147968;   // 16     bb = ||b||^2
constexpr size_t OFF_SUMR  = 147984;   // 64     sum_n resp
constexpr size_t OFF_A     = 148048;   // 16384  A = resp^T X
constexpr size_t OFF_CC0   = 164432;   // 4096   cen cen^T
constexpr size_t OFF_RR    = 168528;   // 4096   resp^T resp
constexpr size_t OFF_CNT   = 172624;   // 64     per-expert token counts (uint)
constexpr size_t OFF_CN2   = 172688;   // 64     ||c_e||^2
constexpr size_t OFF_CB    = 172752;   // 64     c_e . b
constexpr size_t OFF_TSLOT = 172816;   // 2048   per-token writer count (int)
constexpr size_t ZFLOATS   = 174864;
// overwritten-before-read zone (AG.. overlay the dead resp region after routing):
constexpr size_t OFF_RESP  = 174864;   // 131072
constexpr size_t OFF_AG    = 174864;   // 16384  A @ G   (written after resp is dead)
constexpr size_t OFF_MA    = 191248;   // 4096   M A^T
constexpr size_t OFF_AGA   = 195344;   // 4096   (AG) A^T
constexpr size_t OFF_AWB   = 199440;   // 64     A . Wb
constexpr size_t OFF_CHE   = 199504;   // 8448   chunk expert (int)
constexpr size_t OFF_CHB   = 207952;   // 8448   chunk base (int)
constexpr size_t OFF_NCH   = 216400;   // 16     n chunks (int)
constexpr size_t OFF_Y     = 305936;   // 524288 y = X @ pw^T
constexpr size_t OFF_CNEW  = 830224;   // 4194304
constexpr size_t OFF_TIDX  = 5024528;  // 131072 (int) token lists
constexpr size_t OFF_TOKR  = 5155600;  // 131072 token resp values
// total 5286672 floats = 21,146,688 bytes

// ------- centroid stats: cn2[e], cb[e] (d-split x4 for occupancy) -------
__global__ __launch_bounds__(256) void k_cstats(const float* __restrict__ cen,
    const float* __restrict__ bmap, float* __restrict__ cn2, float* __restrict__ cb) {
  int e = blockIdx.x >> 2;
  int d0 = (blockIdx.x & 3) * 16384;
  const float* ce = cen + (size_t)e * D_ + d0;
  const float* bm = bmap + d0;
  float s2 = 0.f, sb = 0.f;
  for (int d = threadIdx.x; d < 16384; d += 256) {
    float v = ce[d];
    s2 = fmaf(v, v, s2);
    sb = fmaf(v, bm[d], sb);
  }
  __shared__ float r0[256], r1[256];
  r0[threadIdx.x] = s2; r1[threadIdx.x] = sb;
  __syncthreads();
  for (int s = 128; s > 0; s >>= 1) {
    if (threadIdx.x < s) { r0[threadIdx.x] += r0[threadIdx.x + s];
                           r1[threadIdx.x] += r1[threadIdx.x + s]; }
    __syncthreads();
  }
  if (threadIdx.x == 0) { atomicAdd(&cn2[e], r0[0]); atomicAdd(&cb[e], r1[0]); }
}

// ---------------- bb = ||b||^2 ----------------
__global__ __launch_bounds__(256) void k_bb(const float* __restrict__ bmap, float* __restrict__ bb) {
  float s = 0.f;
  for (int d = threadIdx.x; d < D_; d += 256) { float v = bmap[d]; s = fmaf(v, v, s); }
  __shared__ float red[256];
  red[threadIdx.x] = s;
  __syncthreads();
  for (int k = 128; k > 0; k >>= 1) {
    if (threadIdx.x < k) red[threadIdx.x] += red[threadIdx.x + k];
    __syncthreads();
  }
  if (threadIdx.x == 0) bb[0] = red[0];
}

// ======== 64x64 tile of A^T A over a k-chunk, atomics out ========
template<int KCHUNK>
__device__ __forceinline__ void gram_tile(const float* __restrict__ Wsrc,
    int d0, int c1, int c2, float* __restrict__ Out, int ldo) {
  __shared__ float Wa[32][68], Wb[32][68];
  int t = threadIdx.x;
  int tx = t & 15, ty = t >> 4;
  int lr = t >> 3, lc = (t & 7) * 8;
  float acc[4][4] = {};
  for (int dk = 0; dk < KCHUNK; dk += 32) {
    const float* Wrow = &Wsrc[(size_t)(d0 + dk + lr) * C_];
    float4 a0 = *(const float4*)&Wrow[c1 + lc];
    float4 a1 = *(const float4*)&Wrow[c1 + lc + 4];
    float4 b0 = *(const float4*)&Wrow[c2 + lc];
    float4 b1 = *(const float4*)&Wrow[c2 + lc + 4];
    __syncthreads();
    *(float4*)&Wa[lr][lc]     = a0;
    *(float4*)&Wa[lr][lc + 4] = a1;
    *(float4*)&Wb[lr][lc]     = b0;
    *(float4*)&Wb[lr][lc + 4] = b1;
    __syncthreads();
    #pragma unroll
    for (int k = 0; k < 32; k++) {
      float4 ra4 = *(const float4*)&Wa[k][ty * 4];
      float4 rb4 = *(const float4*)&Wb[k][tx * 4];
      float ra[4] = {ra4.x, ra4.y, ra4.z, ra4.w};
      float rb[4] = {rb4.x, rb4.y, rb4.z, rb4.w};
      #pragma unroll
      for (int i = 0; i < 4; i++)
        #pragma unroll
        for (int j = 0; j < 4; j++)
          acc[i][j] = fmaf(ra[i], rb[j], acc[i][j]);
    }
  }
  #pragma unroll
  for (int i = 0; i < 4; i++)
    #pragma unroll
    for (int j = 0; j < 4; j++)
      atomicAdd(&Out[(c1 + ty * 4 + i) * ldo + c2 + tx * 4 + j], acc[i][j]);
}

// ---- G = W^T W: upper-tri 64x64 tile pairs (10), ksplit 64x1024 ----
__global__ __launch_bounds__(256) void k_G(const float* __restrict__ W, float* __restrict__ G) {
  int p = blockIdx.y;
  int ti = 0, rem = p;
  while (rem >= 4 - ti) { rem -= 4 - ti; ti++; }
  int tj = ti + rem;
  gram_tile<1024>(W, blockIdx.x * 1024, ti * 64, tj * 64, G, C_);
}

// ---- mirror triangle -> full symmetric G (6 off-diag tile pairs) ----
__global__ __launch_bounds__(256) void k_mirror(float* __restrict__ G) {
  int id = blockIdx.x * 256 + threadIdx.x;   // 96*256 = 24576 = 6*4096
  int p = id >> 12;
  int r = (id >> 6) & 63, cc = id & 63;
  const int t1[6] = {0,0,0,1,1,2}, t2[6] = {1,2,3,2,3,3};
  int a = t1[p] * 64 + r, b = t2[p] * 64 + cc;
  G[b * C_ + a] = G[a * C_ + b];
}

// ---- S = X^T X: full 16 tile pairs, ksplit 8x256 ----
__global__ __launch_bounds__(256) void k_S(const float* __restrict__ x, float* __restrict__ S) {
  int p = blockIdx.y;
  int ti = p >> 2, tj = p & 3;
  gram_tile<256>(x, blockIdx.x * 256, ti * 64, tj * 64, S, C_);
}

// ---------------- Xsum[c] = sum_n X[n,c] ----------------
__global__ __launch_bounds__(256) void k_xsum(const float* __restrict__ x, float* __restrict__ xsum) {
  int n0 = blockIdx.x * 64;
  int c = threadIdx.x;
  float s = 0.f;
  for (int n = 0; n < 64; n++) s += x[(n0 + n) * C_ + c];
  atomicAdd(&xsum[c], s);
}

// -------- Out[64,256] += Arows[64,D] @ W[D,256], ksplit 128x512 ----
__global__ __launch_bounds__(256) void k_mm64(const float* __restrict__ Arows,
    const float* __restrict__ W, float* __restrict__ Out) {
  int d0 = blockIdx.x * 512;
  int c0 = blockIdx.y * 64;
  __shared__ float As[64][17];
  __shared__ float Bs[16][68];
  int t = threadIdx.x;
  int tx = t & 15, ty = t >> 4;
  int ea = t >> 2, k4 = (t & 3) * 4;
  int kb = t >> 4, cc4 = (t & 15) * 4;
  float acc[4][4] = {};
  for (int dk = 0; dk < 512; dk += 16) {
    float4 va = *(const float4*)&Arows[(size_t)ea * D_ + d0 + dk + k4];
    float4 vb = *(const float4*)&W[(size_t)(d0 + dk + kb) * C_ + c0 + cc4];
    __syncthreads();
    As[ea][k4] = va.x; As[ea][k4+1] = va.y; As[ea][k4+2] = va.z; As[ea][k4+3] = va.w;
    *(float4*)&Bs[kb][cc4] = vb;
    __syncthreads();
    #pragma unroll
    for (int k = 0; k < 16; k++) {
      float ra[4], rb[4];
      #pragma unroll
      for (int i = 0; i < 4; i++) ra[i] = As[ty*4 + i][k];
      #pragma unroll
      for (int j = 0; j < 4; j++) rb[j] = Bs[k][tx*4 + j];
      #pragma unroll
      for (int i = 0; i < 4; i++)
        #pragma unroll
        for (int j = 0; j < 4; j++)
          acc[i][j] = fmaf(ra[i], rb[j], acc[i][j]);
    }
  }
  #pragma unroll
  for (int i = 0; i < 4; i++)
    #pragma unroll
    for (int j = 0; j < 4; j++)
      atomicAdd(&Out[(ty*4 + i) * C_ + c0 + tx*4 + j], acc[i][j]);
}

// ---------------- Wb[c] = sum_d b[d] W[d,c] (skips all-zero b chunks) ----------
__global__ __launch_bounds__(256) void k_Wb(const float* __restrict__ bmap,
    const float* __restrict__ W, float* __restrict__ Wb) {
  int d0 = blockIdx.x * 256;
  int c = threadIdx.x;
  __shared__ float bs[256];
  __shared__ int any;
  if (c == 0) any = 0;
  __syncthreads();
  float bv = bmap[d0 + c];
  bs[c] = bv;
  if (bv != 0.f) any = 1;
  __syncthreads();
  if (any == 0) return;
  float s = 0.f;
  for (int d = 0; d < 256; d++) s = fmaf(bs[d], W[(size_t)(d0 + d) * C_ + c], s);
  atomicAdd(&Wb[c], s);
}

// ---------------- y[n,k] = sum_j X[n,j] pw[k,j] ----------------
__global__ __launch_bounds__(256) void k_y(const float* __restrict__ x,
    const float* __restrict__ pw, float* __restrict__ y) {
  int n0 = blockIdx.x * 64, k0 = blockIdx.y * 64;
  __shared__ float Xs[64][17], Ps[64][17];
  int t = threadIdx.x;
  int tx = t & 15, ty = t >> 4;
  int r = t >> 2, q4 = (t & 3) * 4;
  float acc[4][4] = {};
  for (int j0 = 0; j0 < 256; j0 += 16) {
    float4 va = *(const float4*)&x[(n0 + r) * C_ + j0 + q4];
    float4 vb = *(const float4*)&pw[(k0 + r) * C_ + j0 + q4];
    __syncthreads();
    Xs[r][q4] = va.x; Xs[r][q4+1] = va.y; Xs[r][q4+2] = va.z; Xs[r][q4+3] = va.w;
    Ps[r][q4] = vb.x; Ps[r][q4+1] = vb.y; Ps[r][q4+2] = vb.z; Ps[r][q4+3] = vb.w;
    __syncthreads();
    #pragma unroll
    for (int k = 0; k < 16; k++) {
      float ra[4], rb[4];
      #pragma unroll
      for (int i = 0; i < 4; i++) ra[i] = Xs[ty*4 + i][k];
      #pragma unroll
      for (int j = 0; j < 4; j++) rb[j] = Ps[tx*4 + j][k];
      #pragma unroll
      for (int i = 0; i < 4; i++)
        #pragma unroll
        for (int j = 0; j < 4; j++)
          acc[i][j] = fmaf(ra[i], rb[j], acc[i][j]);
    }
  }
  #pragma unroll
  for (int i = 0; i < 4; i++)
    #pragma unroll
    for (int j = 0; j < 4; j++)
      y[(n0 + ty*4 + i) * C_ + k0 + tx*4 + j] = acc[i][j];
}

// ------- resp[n,e]: softmax_e((2(X_n.M_e + cb_e) - cn2_e + gumbel)/tau) --------
__global__ __launch_bounds__(64) void k_resp(const float* __restrict__ x,
    const float* __restrict__ u, const float* __restrict__ M,
    const float* __restrict__ cn2, const float* __restrict__ cb,
    float* __restrict__ resp) {
  int n = blockIdx.x;
  int e = threadIdx.x;
  __shared__ float xs[256];
  *(float4*)&xs[e * 4] = *(const float4*)&x[n * C_ + e * 4];
  __syncthreads();
  const float* Me = M + e * C_;
  float s = 0.f;
  #pragma unroll 8
  for (int j = 0; j < 256; j += 4) {
    float4 m4 = *(const float4*)&Me[j];
    s = fmaf(xs[j],   m4.x, s);
    s = fmaf(xs[j+1], m4.y, s);
    s = fmaf(xs[j+2], m4.z, s);
    s = fmaf(xs[j+3], m4.w, s);
  }
  float uu = u[n * NE + e];
  float g = -logf(-logf(uu));
  float logit = 2.0f * (s + cb[e]) - cn2[e] + g;   // TAU == 1
  float m = logit;
  for (int off = 32; off > 0; off >>= 1) m = fmaxf(m, __shfl_xor(m, off));
  float ex = expf(logit - m);
  float sum = ex;
  for (int off = 32; off > 0; off >>= 1) sum += __shfl_xor(sum, off);
  resp[n * NE + e] = ex / sum;
}

// ------- routing: one thread per token; per-expert lists + writer count -------
// NO cap: every resp > RTHRESH gets a list entry (r3 bug: s<4 cap dropped
// dominant experts with high index -> absmax 15).
__global__ __launch_bounds__(256) void k_route(const float* __restrict__ resp,
    unsigned int* __restrict__ cnt, int* __restrict__ tokidx,
    float* __restrict__ tokr, int* __restrict__ tslot) {
  int n = blockIdx.x * 256 + threadIdx.x;
  int s = 0;
  #pragma unroll 4
  for (int e = 0; e < NE; e++) {
    float r = resp[n * NE + e];
    if (r > RTHRESH) {
      unsigned pos = atomicAdd(&cnt[e], 1u);
      tokidx[e * 2048 + pos] = n;
      tokr[e * 2048 + pos] = r;
      s++;
    }
  }
  tslot[n] = s;
}

// ------- planner: dense chunk table (16 tokens per chunk, uniform expert) -----
__global__ void k_plan(const unsigned int* __restrict__ cnt,
    int* __restrict__ che, int* __restrict__ chb, int* __restrict__ nch) {
  if (threadIdx.x != 0 || blockIdx.x != 0) return;
  int ch = 0;
  for (int e = 0; e < NE; e++) {
    int c = (int)cnt[e];
    for (int b = 0; b < c && ch < CHMAX; b += 16) { che[ch] = e; chb[ch] = b; ch++; }
  }
  nch[0] = ch;
}

// ---------------- A = resp^T X, sumresp  (n-chunks of 16) --------
__global__ __launch_bounds__(256) void k_A(const float* __restrict__ resp,
    const float* __restrict__ x, float* __restrict__ A, float* __restrict__ sumresp) {
  int n0 = blockIdx.x * 16;
  __shared__ float rs[16][65];
  __shared__ float xsh[16][257];
  int t = threadIdx.x;
  for (int i = t; i < 1024; i += 256) rs[i >> 6][i & 63] = resp[n0 * NE + i];
  for (int i = t; i < 4096; i += 256) xsh[i >> 8][i & 255] = x[n0 * C_ + i];
  __syncthreads();
  int e = t & 63, q = t >> 6;
  float acc[64];
  #pragma unroll
  for (int cc = 0; cc < 64; cc++) acc[cc] = 0.f;
  float sr = 0.f;
  for (int nn = 0; nn < 16; nn++) {
    float r = rs[nn][e];
    sr += r;
    const float* xr = &xsh[nn][q * 64];
    #pragma unroll
    for (int cc = 0; cc < 64; cc++) acc[cc] = fmaf(r, xr[cc], acc[cc]);
  }
  #pragma unroll
  for (int cc = 0; cc < 64; cc++) atomicAdd(&A[e * C_ + q * 64 + cc], acc[cc]);
  if (q == 0) atomicAdd(&sumresp[e], sr);
}

// ---------------- RR = resp^T resp ----------------
__global__ __launch_bounds__(256) void k_RR(const float* __restrict__ resp, float* __restrict__ RR) {
  int n0 = blockIdx.x * 64;
  __shared__ float rs[64][65];
  int t = threadIdx.x;
  for (int i = t; i < 4096; i += 256) rs[i >> 6][i & 63] = resp[n0 * NE + i];
  __syncthreads();
  int tx = t & 15, ty = t >> 4;
  float acc[4][4] = {};
  for (int nn = 0; nn < 64; nn++) {
    float a_[4], b_[4];
    #pragma unroll
    for (int i = 0; i < 4; i++) a_[i] = rs[nn][ty*4 + i];
    #pragma unroll
    for (int j = 0; j < 4; j++) b_[j] = rs[nn][tx*4 + j];
    #pragma unroll
    for (int i = 0; i < 4; i++)
      #pragma unroll
      for (int j = 0; j < 4; j++)
        acc[i][j] = fmaf(a_[i], b_[j], acc[i][j]);
  }
  #pragma unroll
  for (int i = 0; i < 4; i++)
    #pragma unroll
    for (int j = 0; j < 4; j++)
      atomicAdd(&RR[(ty*4 + i) * NE + tx*4 + j], acc[i][j]);
}

// ---------------- AG = A @ G (full sym G), AWb[e] = A_e . Wb ----------------
__global__ __launch_bounds__(256) void k_ag(const float* __restrict__ A,
    const float* __restrict__ G, const float* __restrict__ Wb,
    float* __restrict__ AG, float* __restrict__ AWb) {
  int e = blockIdx.x, c = threadIdx.x;
  float s = 0.f;
  for (int cp = 0; cp < C_; cp++) s = fmaf(A[e * C_ + cp], G[cp * C_ + c], s);
  AG[e * C_ + c] = s;
  float p = A[e * C_ + c] * Wb[c];
  __shared__ float red[256];
  red[c] = p;
  __syncthreads();
  for (int k = 128; k > 0; k >>= 1) {
    if (c < k) red[c] += red[c + k];
    __syncthreads();
  }
  if (c == 0) AWb[e] = red[0];
}

// ---------------- MA = M A^T, AGA = AG A^T (64x64 each) ----------------
__global__ __launch_bounds__(256) void k_small64(const float* __restrict__ M,
    const float* __restrict__ A, const float* __restrict__ AG,
    float* __restrict__ MA, float* __restrict__ AGA) {
  int e = blockIdx.x;
  int f = threadIdx.x >> 2, q = threadIdx.x & 3;
  float s1 = 0.f, s2 = 0.f;
  for (int c = q * 64; c < q * 64 + 64; c++) {
    float a = A[f * C_ + c];
    s1 = fmaf(M[e * C_ + c], a, s1);
    s2 = fmaf(AG[e * C_ + c], a, s2);
  }
  __shared__ float r1[256], r2[256];
  r1[threadIdx.x] = s1; r2[threadIdx.x] = s2;
  __syncthreads();
  if (q == 0) {
    MA[e * NE + f]  = r1[f*4] + r1[f*4+1] + r1[f*4+2] + r1[f*4+3];
    AGA[e * NE + f] = r2[f*4] + r2[f*4+1] + r2[f*4+2] + r2[f*4+3];
  }
}

// ------- cnew[e,d] = decay*c + alpha*(A_e.W_d + sumresp_e*b_d) -------
__global__ __launch_bounds__(256) void k_cnew(const float* __restrict__ A,
    const float* __restrict__ sumresp, const float* __restrict__ cen,
    const float* __restrict__ bmap, const float* __restrict__ W,
    float* __restrict__ cnew) {
  int d0 = blockIdx.x * 64;
  __shared__ float As[64][260];
  __shared__ float Ws[64][17];
  int t = threadIdx.x;
  for (int i = t; i < 16384; i += 256) As[i >> 8][i & 255] = A[i];
  int tx = t & 15, ty = t >> 4;
  int dd = t >> 2, k4 = (t & 3) * 4;
  float acc[4][4] = {};
  for (int c0 = 0; c0 < 256; c0 += 16) {
    float4 w4 = *(const float4*)&W[(size_t)(d0 + dd) * C_ + c0 + k4];
    __syncthreads();
    Ws[dd][k4] = w4.x; Ws[dd][k4+1] = w4.y; Ws[dd][k4+2] = w4.z; Ws[dd][k4+3] = w4.w;
    __syncthreads();
    #pragma unroll
    for (int k = 0; k < 16; k++) {
      float ra[4], rb[4];
      #pragma unroll
      for (int i = 0; i < 4; i++) ra[i] = As[ty*4 + i][c0 + k];
      #pragma unroll
      for (int j = 0; j < 4; j++) rb[j] = Ws[tx*4 + j][k];
      #pragma unroll
      for (int i = 0; i < 4; i++)
        #pragma unroll
        for (int j = 0; j < 4; j++)
          acc[i][j] = fmaf(ra[i], rb[j], acc[i][j]);
    }
  }
  #pragma unroll
  for (int i = 0; i < 4; i++) {
    int e = ty*4 + i;
    float sr = sumresp[e];
    #pragma unroll
    for (int j = 0; j < 4; j++) {
      int d = d0 + tx*4 + j;
      cnew[(size_t)e * D_ + d] = DECAYF * cen[(size_t)e * D_ + d]
                               + ALPHA * (acc[i][j] + sr * bmap[d]);
    }
  }
}

// ---------------- CC0 = cen cen^T ----------------
__global__ __launch_bounds__(256) void k_CC(const float* __restrict__ cen, float* __restrict__ CC0) {
  int d0 = blockIdx.x * 512;
  __shared__ float cs[64][17];
  int t = threadIdx.x;
  int tx = t & 15, ty = t >> 4;
  int ea = t >> 2, k4 = (t & 3) * 4;
  float acc[4][4] = {};
  for (int dk = 0; dk < 512; dk += 16) {
    float4 v = *(const float4*)&cen[(size_t)ea * D_ + d0 + dk + k4];
    __syncthreads();
    cs[ea][k4] = v.x; cs[ea][k4+1] = v.y; cs[ea][k4+2] = v.z; cs[ea][k4+3] = v.w;
    __syncthreads();
    #pragma unroll
    for (int k = 0; k < 16; k++) {
      float a_[4], b_[4];
      #pragma unroll
      for (int i = 0; i < 4; i++) a_[i] = cs[ty*4 + i][k];
      #pragma unroll
      for (int j = 0; j < 4; j++) b_[j] = cs[tx*4 + j][k];
      #pragma unroll
      for (int i = 0; i < 4; i++)
        #pragma unroll
        for (int j = 0; j < 4; j++)
          acc[i][j] = fmaf(a_[i], b_[j], acc[i][j]);
    }
  }
  #pragma unroll
  for (int i = 0; i < 4; i++)
    #pragma unroll
    for (int j = 0; j < 4; j++)
      atomicAdd(&CC0[(ty*4 + i) * NE + tx*4 + j], acc[i][j]);
}

// ---------------- out init with bias ----------------
__global__ __launch_bounds__(256) void k_bias(const float* __restrict__ pwB, float* __restrict__ out) {
  int idx = blockIdx.x * 256 + threadIdx.x;
  out[idx] = pwB[idx & 255];
}

// ------- stage A: dense grouped GEMM, 16 tok x 128 out per block -------
// out[n, i0+i] += r * sum_k cnew[e, (i0+i)*256+k] * y[n,k]
// single-writer tokens (tslot==1): plain RMW on bias-initialized out; else atomic.
// Grid-stride over chunks (uniform trip count; sync at loop top protects LDS).
__global__ __launch_bounds__(256) void k_sA(const int* __restrict__ che,
    const int* __restrict__ chb, const int* __restrict__ nch,
    const unsigned int* __restrict__ cnt, const int* __restrict__ tokidx,
    const float* __restrict__ tokr, const int* __restrict__ tslot,
    const float* __restrict__ y, const float* __restrict__ cnew,
    float* __restrict__ out) {
  int nchv = nch[0];
  int i0 = blockIdx.y * 128;
  __shared__ int nsh[16]; __shared__ float rsh[16]; __shared__ int wsh[16];
  __shared__ float Ys[16][260];
  __shared__ float Bs[32][132];
  int t = threadIdx.x;
  for (int ch = blockIdx.x; ch < nchv; ch += SA_GRIDX) {
    int e = che[ch], base = chb[ch];
    int c = (int)cnt[e];
    __syncthreads();   // protect prior iteration's LDS reads
    if (t < 16) {
      int idx = base + t;
      if (idx < c) {
        int n = tokidx[e * 2048 + idx];
        nsh[t] = n; rsh[t] = tokr[e * 2048 + idx]; wsh[t] = tslot[n];
      } else { nsh[t] = 0; rsh[t] = 0.f; wsh[t] = 2; }
    }
    __syncthreads();
    {  // stage y rows
      int row = t >> 4, c0 = (t & 15) * 16;
      const float* yr = &y[nsh[row] * C_ + c0];
      float4 v0 = *(const float4*)&yr[0];
      float4 v1 = *(const float4*)&yr[4];
      float4 v2 = *(const float4*)&yr[8];
      float4 v3 = *(const float4*)&yr[12];
      *(float4*)&Ys[row][c0]      = v0;
      *(float4*)&Ys[row][c0 + 4]  = v1;
      *(float4*)&Ys[row][c0 + 8]  = v2;
      *(float4*)&Ys[row][c0 + 12] = v3;
    }
    int tx = t & 31, ty = t >> 5;         // tx: 32 i-groups of 4; ty: 8 tok-pairs
    int br = t >> 1, bk = (t & 1) * 16;   // B load: row br (128), 16 k each
    float acc[2][4] = {};
    for (int k0 = 0; k0 < 256; k0 += 32) {
      const float* Brow = &cnew[(size_t)e * D_ + (size_t)(i0 + br) * C_ + k0 + bk];
      float4 b0 = *(const float4*)&Brow[0];
      float4 b1 = *(const float4*)&Brow[4];
      float4 b2 = *(const float4*)&Brow[8];
      float4 b3 = *(const float4*)&Brow[12];
      __syncthreads();
      Bs[bk+0][br]  = b0.x; Bs[bk+1][br]  = b0.y; Bs[bk+2][br]  = b0.z; Bs[bk+3][br]  = b0.w;
      Bs[bk+4][br]  = b1.x; Bs[bk+5][br]  = b1.y; Bs[bk+6][br]  = b1.z; Bs[bk+7][br]  = b1.w;
      Bs[bk+8][br]  = b2.x; Bs[bk+9][br]  = b2.y; Bs[bk+10][br] = b2.z; Bs[bk+11][br] = b2.w;
      Bs[bk+12][br] = b3.x; Bs[bk+13][br] = b3.y; Bs[bk+14][br] = b3.z; Bs[bk+15][br] = b3.w;
      __syncthreads();
      #pragma unroll
      for (int kk = 0; kk < 32; kk++) {
        float a0 = Ys[ty*2 + 0][k0 + kk];
        float a1 = Ys[ty*2 + 1][k0 + kk];
        float4 bv = *(const float4*)&Bs[kk][tx*4];
        acc[0][0] = fmaf(a0, bv.x, acc[0][0]); acc[0][1] = fmaf(a0, bv.y, acc[0][1]);
        acc[0][2] = fmaf(a0, bv.z, acc[0][2]); acc[0][3] = fmaf(a0, bv.w, acc[0][3]);
        acc[1][0] = fmaf(a1, bv.x, acc[1][0]); acc[1][1] = fmaf(a1, bv.y, acc[1][1]);
        acc[1][2] = fmaf(a1, bv.z, acc[1][2]); acc[1][3] = fmaf(a1, bv.w, acc[1][3]);
      }
    }
    #pragma unroll
    for (int i = 0; i < 2; i++) {
      int tk = ty*2 + i;
      float r = rsh[tk];
      if (r == 0.f) continue;
      int n = nsh[tk];
      float* op = &out[n * C_ + i0 + tx*4];
      if (wsh[tk] == 1) {
        float4 cur = *(const float4*)op;
        cur.x += r * acc[i][0]; cur.y += r * acc[i][1];
        cur.z += r * acc[i][2]; cur.w += r * acc[i][3];
        *(float4*)op = cur;
      } else {
        atomicAdd(op + 0, r * acc[i][0]);
        atomicAdd(op + 1, r * acc[i][1]);
        atomicAdd(op + 2, r * acc[i][2]);
        atomicAdd(op + 3, r * acc[i][3]);
      }
    }
  }
}

// ---------------- loss assembly ----------------
__global__ __launch_bounds__(256) void k_finalize(
    const float* __restrict__ S, const float* __restrict__ G,
    const float* __restrict__ M, const float* __restrict__ A,
    const float* __restrict__ AG, const float* __restrict__ CC0,
    const float* __restrict__ RR, const float* __restrict__ MA,
    const float* __restrict__ AGA, const float* __restrict__ Xsum,
    const float* __restrict__ Wb, const float* __restrict__ bb,
    const float* __restrict__ sr, const float* __restrict__ cb,
    const float* __restrict__ AWb, float* __restrict__ out) {
  int t = threadIdx.x;
  float a_gs = 0.f, a_am = 0.f, a_aag = 0.f;
  for (int i = t; i < 65536; i += 256) a_gs = fmaf(G[i], S[i], a_gs);
  for (int i = t; i < 16384; i += 256) {
    float a = A[i];
    a_am  = fmaf(M[i], a, a_am);
    a_aag = fmaf(AG[i], a, a_aag);
  }
  float a_cc = 0.f, a_ma = 0.f, a_aga = 0.f, a_cbsr = 0.f, a_awbsr = 0.f, a_srsr = 0.f;
  for (int p = t; p < 4096; p += 256) {
    float r = RR[p];
    int e = p >> 6, f = p & 63;
    float srf = sr[f];
    a_cc    = fmaf(r, CC0[p], a_cc);
    a_ma    = fmaf(r, MA[p], a_ma);
    a_aga   = fmaf(r, AGA[p], a_aga);
    a_cbsr  = fmaf(r * cb[e], srf, a_cbsr);
    a_awbsr = fmaf(r * AWb[e], srf, a_awbsr);
    a_srsr  = fmaf(r * sr[e], srf, a_srsr);
  }
  float a_xw = Xsum[t] * Wb[t];
  float a_srcb = 0.f, a_srawb = 0.f, a_sr2 = 0.f;
  if (t < 64) { float s = sr[t]; a_srcb = s * cb[t]; a_srawb = s * AWb[t]; a_sr2 = s * s; }
  float v[13] = {a_gs, a_am, a_aag, a_cc, a_ma, a_aga, a_cbsr, a_awbsr, a_srsr,
                 a_xw, a_srcb, a_srawb, a_sr2};
  __shared__ float red[256];
  __shared__ float tot[13];
  for (int q = 0; q < 13; q++) {
    red[t] = v[q];
    __syncthreads();
    for (int s2 = 128; s2 > 0; s2 >>= 1) {
      if (t < s2) red[t] += red[t + s2];
      __syncthreads();
    }
    if (t == 0) tot[q] = red[0];
    __syncthreads();
  }
  if (t == 0) {
    const float q = DECAYF, al = ALPHA;
    float bbv = bb[0];
    float sumkeyf2 = tot[0] + 2.f * tot[9] + 2048.f * bbv;
    float cross = q * (tot[1] + tot[10]) + al * (tot[2] + 2.f * tot[11] + bbv * tot[12]);
    float sumq2 = q*q * tot[3] + 2.f*q*al * (tot[4] + tot[6])
                + al*al * (tot[5] + 2.f * tot[7] + bbv * tot[8]);
    out[524288] = (0.25f / (2048.0f * 65536.0f)) * (sumkeyf2 - 2.f * cross + sumq2);
  }
}

extern "C" void kernel_launch(void* const* d_in, const int* in_sizes, int n_in,
                              void* d_out, int out_size, void* d_ws, size_t ws_size,
                              hipStream_t stream) {
  const float* x    = (const float*)d_in[0];
  const float* u    = (const float*)d_in[1];
  const float* Wm   = (const float*)d_in[2];
  const float* bmap = (const float*)d_in[3];
  const float* pw   = (const float*)d_in[4];
  const float* pwB  = (const float*)d_in[5];
  const float* cen  = (const float*)d_in[6];
  float* out = (float*)d_out;
  float* ws  = (float*)d_ws;

  float* S_      = ws + OFF_S;
  float* Xsum    = ws + OFF_XSUM;
  float* G       = ws + OFF_G;
  float* M       = ws + OFF_M;
  float* Wb      = ws + OFF_WB;
  float* bb      = ws + OFF_BB;
  float* sumresp = ws + OFF_SUMR;
  float* A       = ws + OFF_A;
  float* CC0     = ws + OFF_CC0;
  float* RR      = ws + OFF_RR;
  unsigned int* cnt = (unsigned int*)(ws + OFF_CNT);
  float* cn2     = ws + OFF_CN2;
  float* cb      = ws + OFF_CB;
  int*   tslot   = (int*)(ws + OFF_TSLOT);
  float* resp    = ws + OFF_RESP;
  float* AG      = ws + OFF_AG;
  float* MA      = ws + OFF_MA;
  float* AGA     = ws + OFF_AGA;
  float* AWb     = ws + OFF_AWB;
  int*   che     = (int*)(ws + OFF_CHE);
  int*   chb     = (int*)(ws + OFF_CHB);
  int*   nch     = (int*)(ws + OFF_NCH);
  float* y       = ws + OFF_Y;
  float* cnew    = ws + OFF_CNEW;
  int*   tokidx  = (int*)(ws + OFF_TIDX);
  float* tokr    = ws + OFF_TOKR;

  hipMemsetAsync(d_ws, 0, ZFLOATS * sizeof(float), stream);

  k_cstats<<<256, 256, 0, stream>>>(cen, bmap, cn2, cb);
  k_bb<<<1, 256, 0, stream>>>(bmap, bb);
  k_S<<<dim3(8, 16), 256, 0, stream>>>(x, S_);
  k_xsum<<<32, 256, 0, stream>>>(x, Xsum);
  k_G<<<dim3(64, 10), 256, 0, stream>>>(Wm, G);
  k_mirror<<<96, 256, 0, stream>>>(G);
  k_CC<<<128, 256, 0, stream>>>(cen, CC0);
  k_mm64<<<dim3(128, 4), 256, 0, stream>>>(cen, Wm, M);
  k_Wb<<<256, 256, 0, stream>>>(bmap, Wm, Wb);
  k_y<<<dim3(32, 4), 256, 0, stream>>>(x, pw, y);
  k_resp<<<2048, 64, 0, stream>>>(x, u, M, cn2, cb, resp);
  k_route<<<8, 256, 0, stream>>>(resp, cnt, tokidx, tokr, tslot);
  k_A<<<128, 256, 0, stream>>>(resp, x, A, sumresp);
  k_RR<<<32, 256, 0, stream>>>(resp, RR);
  k_plan<<<1, 64, 0, stream>>>(cnt, che, chb, nch);
  k_ag<<<64, 256, 0, stream>>>(A, G, Wb, AG, AWb);
  k_small64<<<64, 256, 0, stream>>>(M, A, AG, MA, AGA);
  k_cnew<<<1024, 256, 0, stream>>>(A, sumresp, cen, bmap, Wm, cnew);
  k_bias<<<2048, 256, 0, stream>>>(pwB, out);
  k_sA<<<dim3(SA_GRIDX, 2), 256, 0, stream>>>(che, chb, nch, cnt, tokidx, tokr,
                                              tslot, y, cnew, out);
  k_finalize<<<1, 256, 0, stream>>>(S_, G, M, A, AG, CC0, RR, MA, AGA, Xsum, Wb,
                                    bb, sumresp, cb, AWb, out);
}

// Round 5
// 741.151 us; speedup vs baseline: 1.6872x; 1.1830x over previous
//
#include <hip/hip_runtime.h>

// Problem dims
constexpr int N_TOK = 2048;   // T*B
constexpr int C_    = 256;    // in features (== R == OUT)
constexpr int NE    = 64;     // experts
constexpr int D_    = 65536;  // R*OUT centroid dim
constexpr float DECAYF = 0.999f;
constexpr float OMD    = 0.001f;          // f32(1.0 - 0.999) as jnp uses
constexpr float ALPHA  = OMD / 2048.0f;   // (1-decay)/N
constexpr float RTHRESH = 1e-5f;          // routing weight cutoff
constexpr int CHMAX = 8448;               // >= worst-case sum_e ceil(cnt_e/16)
constexpr int SA_GRIDX = 512;             // k_sA grid-stride width

// ---------- workspace layout (float offsets) ----------
// zero-initialized zone:
constexpr size_t OFF_S     = 0;        // 65536  S = X^T X (full)
constexpr size_t OFF_XSUM  = 65536;    // 256
constexpr size_t OFF_G     = 65792;    // 65536  G = W^T W (triangle, mirrored to full)
constexpr size_t OFF_M     = 131328;   // 16384  M = cen @ W
constexpr size_t OFF_WB    = 147712;   // 256    Wb = b^T W
constexpr size_t OFF_BB    = 147968;   // 16     bb = ||b||^2
constexpr size_t OFF_SUMR  = 147984;   // 64     sum_n resp
constexpr size_t OFF_A     = 148048;   // 16384  A = resp^T X
constexpr size_t OFF_CC0   = 164432;   // 4096   cen cen^T
constexpr size_t OFF_RR    = 168528;   // 4096   resp^T resp
constexpr size_t OFF_CNT   = 172624;   // 64     per-expert token counts (uint)
constexpr size_t OFF_CN2   = 172688;   // 64     ||c_e||^2
constexpr size_t OFF_CB    = 172752;   // 64     c_e . b
constexpr size_t OFF_TSLOT = 172816;   // 2048   per-token writer count (int)
constexpr size_t ZFLOATS   = 174864;
// overwritten-before-read zone (AG.. overlay the dead resp region after use):
constexpr size_t OFF_RESP  = 174864;   // 131072
constexpr size_t OFF_AG    = 174864;   // 16384  A @ G   (written after resp is dead)
constexpr size_t OFF_MA    = 191248;   // 4096   M A^T
constexpr size_t OFF_AGA   = 195344;   // 4096   (AG) A^T
constexpr size_t OFF_AWB   = 199440;   // 64     A . Wb
constexpr size_t OFF_CHE   = 199504;   // 8448   chunk expert (int)
constexpr size_t OFF_CHB   = 207952;   // 8448   chunk base (int)
constexpr size_t OFF_NCH   = 216400;   // 16     n chunks (int)
constexpr size_t OFF_Y     = 305936;   // 524288 y = X @ pw^T
constexpr size_t OFF_CNEW  = 830224;   // 4194304
constexpr size_t OFF_TIDX  = 5024528;  // 131072 (int) token lists
constexpr size_t OFF_TOKR  = 5155600;  // 131072 token resp values
// total 5286672 floats = 21,146,688 bytes

// ------- centroid stats: cn2[e], cb[e] (d-split x4 for occupancy) -------
__global__ __launch_bounds__(256) void k_cstats(const float* __restrict__ cen,
    const float* __restrict__ bmap, float* __restrict__ cn2, float* __restrict__ cb) {
  int e = blockIdx.x >> 2;
  int d0 = (blockIdx.x & 3) * 16384;
  const float* ce = cen + (size_t)e * D_ + d0;
  const float* bm = bmap + d0;
  float s2 = 0.f, sb = 0.f;
  for (int d = threadIdx.x; d < 16384; d += 256) {
    float v = ce[d];
    s2 = fmaf(v, v, s2);
    sb = fmaf(v, bm[d], sb);
  }
  __shared__ float r0[256], r1[256];
  r0[threadIdx.x] = s2; r1[threadIdx.x] = sb;
  __syncthreads();
  for (int s = 128; s > 0; s >>= 1) {
    if (threadIdx.x < s) { r0[threadIdx.x] += r0[threadIdx.x + s];
                           r1[threadIdx.x] += r1[threadIdx.x + s]; }
    __syncthreads();
  }
  if (threadIdx.x == 0) { atomicAdd(&cn2[e], r0[0]); atomicAdd(&cb[e], r1[0]); }
}

// ---------------- bb = ||b||^2 ----------------
__global__ __launch_bounds__(256) void k_bb(const float* __restrict__ bmap, float* __restrict__ bb) {
  float s = 0.f;
  for (int d = threadIdx.x; d < D_; d += 256) { float v = bmap[d]; s = fmaf(v, v, s); }
  __shared__ float red[256];
  red[threadIdx.x] = s;
  __syncthreads();
  for (int k = 128; k > 0; k >>= 1) {
    if (threadIdx.x < k) red[threadIdx.x] += red[threadIdx.x + k];
    __syncthreads();
  }
  if (threadIdx.x == 0) bb[0] = red[0];
}

// ======== generalized 64x64 tile: Out[ro+i,co+j] += sum_k Aop[k,ca+i]*Bop[k,cb+j]
// Aop/Bop are k-major (row k, ld stride). 16x16 threads, 4x4 per thread.
// ra: 4-distinct-float4 broadcast (free); rb: stride-16B 2-way (free per m136).
// Atomics fan-in = gridDim ksplit (keep <= 8-ish; r4 lesson: 128 contenders = 170us).
template<int KCHUNK>
__device__ __forceinline__ void gemm_tt_tile(
    const float* __restrict__ Aop, int lda, int ca,
    const float* __restrict__ Bop, int ldb, int cb,
    int d0, float* __restrict__ Out, int ldo, int ro, int co) {
  __shared__ float Wa[32][68], Wb[32][68];
  int t = threadIdx.x;
  int tx = t & 15, ty = t >> 4;
  int lr = t >> 3, lc = (t & 7) * 8;
  float acc[4][4] = {};
  for (int dk = 0; dk < KCHUNK; dk += 32) {
    const float* Arow = &Aop[(size_t)(d0 + dk + lr) * lda + ca];
    const float* Brow = &Bop[(size_t)(d0 + dk + lr) * ldb + cb];
    float4 a0 = *(const float4*)&Arow[lc];
    float4 a1 = *(const float4*)&Arow[lc + 4];
    float4 b0 = *(const float4*)&Brow[lc];
    float4 b1 = *(const float4*)&Brow[lc + 4];
    __syncthreads();
    *(float4*)&Wa[lr][lc]     = a0;
    *(float4*)&Wa[lr][lc + 4] = a1;
    *(float4*)&Wb[lr][lc]     = b0;
    *(float4*)&Wb[lr][lc + 4] = b1;
    __syncthreads();
    #pragma unroll
    for (int k = 0; k < 32; k++) {
      float4 ra4 = *(const float4*)&Wa[k][ty * 4];
      float4 rb4 = *(const float4*)&Wb[k][tx * 4];
      float ra[4] = {ra4.x, ra4.y, ra4.z, ra4.w};
      float rb[4] = {rb4.x, rb4.y, rb4.z, rb4.w};
      #pragma unroll
      for (int i = 0; i < 4; i++)
        #pragma unroll
        for (int j = 0; j < 4; j++)
          acc[i][j] = fmaf(ra[i], rb[j], acc[i][j]);
    }
  }
  #pragma unroll
  for (int i = 0; i < 4; i++)
    #pragma unroll
    for (int j = 0; j < 4; j++)
      atomicAdd(&Out[(size_t)(ro + ty * 4 + i) * ldo + co + tx * 4 + j], acc[i][j]);
}

// ---- G = W^T W: upper-tri 64x64 tile pairs (10), ksplit 64x1024 ----
__global__ __launch_bounds__(256) void k_G(const float* __restrict__ W, float* __restrict__ G) {
  int p = blockIdx.y;
  int ti = 0, rem = p;
  while (rem >= 4 - ti) { rem -= 4 - ti; ti++; }
  int tj = ti + rem;
  gemm_tt_tile<1024>(W, C_, ti * 64, W, C_, tj * 64, blockIdx.x * 1024,
                     G, C_, ti * 64, tj * 64);
}

// ---- mirror triangle -> full symmetric G (6 off-diag tile pairs) ----
__global__ __launch_bounds__(256) void k_mirror(float* __restrict__ G) {
  int id = blockIdx.x * 256 + threadIdx.x;   // 96*256 = 24576 = 6*4096
  int p = id >> 12;
  int r = (id >> 6) & 63, cc = id & 63;
  const int t1[6] = {0,0,0,1,1,2}, t2[6] = {1,2,3,2,3,3};
  int a = t1[p] * 64 + r, b = t2[p] * 64 + cc;
  G[b * C_ + a] = G[a * C_ + b];
}

// ---- S = X^T X: full 16 tile pairs, ksplit 8x256 ----
__global__ __launch_bounds__(256) void k_S(const float* __restrict__ x, float* __restrict__ S) {
  int p = blockIdx.y;
  int ti = p >> 2, tj = p & 3;
  gemm_tt_tile<256>(x, C_, ti * 64, x, C_, tj * 64, blockIdx.x * 256,
                    S, C_, ti * 64, tj * 64);
}

// ---- A = resp^T X: [64,2048]@[2048,256]; 4 C-tiles x ksplit 8x256 = 32 blocks ----
__global__ __launch_bounds__(256) void k_A2(const float* __restrict__ resp,
    const float* __restrict__ x, float* __restrict__ A) {
  gemm_tt_tile<256>(resp, NE, 0, x, C_, blockIdx.y * 64, blockIdx.x * 256,
                    A, C_, 0, blockIdx.y * 64);
}

// ---- RR = resp^T resp: single 64x64 tile, ksplit 8x256 = 8 blocks ----
__global__ __launch_bounds__(256) void k_RR2(const float* __restrict__ resp,
    float* __restrict__ RR) {
  gemm_tt_tile<256>(resp, NE, 0, resp, NE, 0, blockIdx.x * 256, RR, NE, 0, 0);
}

// ---- sumresp[e] = sum_n resp[n,e]; 8 blocks, coalesced, 8-contender atomics ----
__global__ __launch_bounds__(256) void k_sr(const float* __restrict__ resp,
    float* __restrict__ sumresp) {
  int e = threadIdx.x & 63, part = threadIdx.x >> 6;
  int n0 = blockIdx.x * 256 + part * 64;
  float s = 0.f;
  for (int n = n0; n < n0 + 64; n++) s += resp[n * NE + e];
  __shared__ float red[256];
  red[threadIdx.x] = s;
  __syncthreads();
  if (part == 0)
    atomicAdd(&sumresp[e], red[e] + red[64 + e] + red[128 + e] + red[192 + e]);
}

// ---------------- Xsum[c] = sum_n X[n,c] ----------------
__global__ __launch_bounds__(256) void k_xsum(const float* __restrict__ x, float* __restrict__ xsum) {
  int n0 = blockIdx.x * 64;
  int c = threadIdx.x;
  float s = 0.f;
  for (int n = 0; n < 64; n++) s += x[(n0 + n) * C_ + c];
  atomicAdd(&xsum[c], s);
}

// -------- Out[64,256] += Arows[64,D] @ W[D,256], ksplit 128x512 ----
__global__ __launch_bounds__(256) void k_mm64(const float* __restrict__ Arows,
    const float* __restrict__ W, float* __restrict__ Out) {
  int d0 = blockIdx.x * 512;
  int c0 = blockIdx.y * 64;
  __shared__ float As[64][17];
  __shared__ float Bs[16][68];
  int t = threadIdx.x;
  int tx = t & 15, ty = t >> 4;
  int ea = t >> 2, k4 = (t & 3) * 4;
  int kb = t >> 4, cc4 = (t & 15) * 4;
  float acc[4][4] = {};
  for (int dk = 0; dk < 512; dk += 16) {
    float4 va = *(const float4*)&Arows[(size_t)ea * D_ + d0 + dk + k4];
    float4 vb = *(const float4*)&W[(size_t)(d0 + dk + kb) * C_ + c0 + cc4];
    __syncthreads();
    As[ea][k4] = va.x; As[ea][k4+1] = va.y; As[ea][k4+2] = va.z; As[ea][k4+3] = va.w;
    *(float4*)&Bs[kb][cc4] = vb;
    __syncthreads();
    #pragma unroll
    for (int k = 0; k < 16; k++) {
      float ra[4], rb[4];
      #pragma unroll
      for (int i = 0; i < 4; i++) ra[i] = As[ty*4 + i][k];
      #pragma unroll
      for (int j = 0; j < 4; j++) rb[j] = Bs[k][tx*4 + j];
      #pragma unroll
      for (int i = 0; i < 4; i++)
        #pragma unroll
        for (int j = 0; j < 4; j++)
          acc[i][j] = fmaf(ra[i], rb[j], acc[i][j]);
    }
  }
  #pragma unroll
  for (int i = 0; i < 4; i++)
    #pragma unroll
    for (int j = 0; j < 4; j++)
      atomicAdd(&Out[(ty*4 + i) * C_ + c0 + tx*4 + j], acc[i][j]);
}

// ---------------- Wb[c] = sum_d b[d] W[d,c] (skips all-zero b chunks) ----------
__global__ __launch_bounds__(256) void k_Wb(const float* __restrict__ bmap,
    const float* __restrict__ W, float* __restrict__ Wb) {
  int d0 = blockIdx.x * 256;
  int c = threadIdx.x;
  __shared__ float bs[256];
  __shared__ int any;
  if (c == 0) any = 0;
  __syncthreads();
  float bv = bmap[d0 + c];
  bs[c] = bv;
  if (bv != 0.f) any = 1;
  __syncthreads();
  if (any == 0) return;
  float s = 0.f;
  for (int d = 0; d < 256; d++) s = fmaf(bs[d], W[(size_t)(d0 + d) * C_ + c], s);
  atomicAdd(&Wb[c], s);
}

// ---------------- y[n,k] = sum_j X[n,j] pw[k,j] ----------------
__global__ __launch_bounds__(256) void k_y(const float* __restrict__ x,
    const float* __restrict__ pw, float* __restrict__ y) {
  int n0 = blockIdx.x * 64, k0 = blockIdx.y * 64;
  __shared__ float Xs[64][17], Ps[64][17];
  int t = threadIdx.x;
  int tx = t & 15, ty = t >> 4;
  int r = t >> 2, q4 = (t & 3) * 4;
  float acc[4][4] = {};
  for (int j0 = 0; j0 < 256; j0 += 16) {
    float4 va = *(const float4*)&x[(n0 + r) * C_ + j0 + q4];
    float4 vb = *(const float4*)&pw[(k0 + r) * C_ + j0 + q4];
    __syncthreads();
    Xs[r][q4] = va.x; Xs[r][q4+1] = va.y; Xs[r][q4+2] = va.z; Xs[r][q4+3] = va.w;
    Ps[r][q4] = vb.x; Ps[r][q4+1] = vb.y; Ps[r][q4+2] = vb.z; Ps[r][q4+3] = vb.w;
    __syncthreads();
    #pragma unroll
    for (int k = 0; k < 16; k++) {
      float ra[4], rb[4];
      #pragma unroll
      for (int i = 0; i < 4; i++) ra[i] = Xs[ty*4 + i][k];
      #pragma unroll
      for (int j = 0; j < 4; j++) rb[j] = Ps[tx*4 + j][k];
      #pragma unroll
      for (int i = 0; i < 4; i++)
        #pragma unroll
        for (int j = 0; j < 4; j++)
          acc[i][j] = fmaf(ra[i], rb[j], acc[i][j]);
    }
  }
  #pragma unroll
  for (int i = 0; i < 4; i++)
    #pragma unroll
    for (int j = 0; j < 4; j++)
      y[(n0 + ty*4 + i) * C_ + k0 + tx*4 + j] = acc[i][j];
}

// ------- resp[n,e]: softmax_e((2(X_n.M_e + cb_e) - cn2_e + gumbel)/tau) --------
__global__ __launch_bounds__(64) void k_resp(const float* __restrict__ x,
    const float* __restrict__ u, const float* __restrict__ M,
    const float* __restrict__ cn2, const float* __restrict__ cb,
    float* __restrict__ resp) {
  int n = blockIdx.x;
  int e = threadIdx.x;
  __shared__ float xs[256];
  *(float4*)&xs[e * 4] = *(const float4*)&x[n * C_ + e * 4];
  __syncthreads();
  const float* Me = M + e * C_;
  float s = 0.f;
  #pragma unroll 8
  for (int j = 0; j < 256; j += 4) {
    float4 m4 = *(const float4*)&Me[j];
    s = fmaf(xs[j],   m4.x, s);
    s = fmaf(xs[j+1], m4.y, s);
    s = fmaf(xs[j+2], m4.z, s);
    s = fmaf(xs[j+3], m4.w, s);
  }
  float uu = u[n * NE + e];
  float g = -logf(-logf(uu));
  float logit = 2.0f * (s + cb[e]) - cn2[e] + g;   // TAU == 1
  float m = logit;
  for (int off = 32; off > 0; off >>= 1) m = fmaxf(m, __shfl_xor(m, off));
  float ex = expf(logit - m);
  float sum = ex;
  for (int off = 32; off > 0; off >>= 1) sum += __shfl_xor(sum, off);
  resp[n * NE + e] = ex / sum;
}

// ------- routing: one thread per token; per-expert lists + writer count -------
// NO cap (r3 bug: index-order cap dropped dominant experts -> absmax 15).
__global__ __launch_bounds__(256) void k_route(const float* __restrict__ resp,
    unsigned int* __restrict__ cnt, int* __restrict__ tokidx,
    float* __restrict__ tokr, int* __restrict__ tslot) {
  int n = blockIdx.x * 256 + threadIdx.x;
  int s = 0;
  #pragma unroll 4
  for (int e = 0; e < NE; e++) {
    float r = resp[n * NE + e];
    if (r > RTHRESH) {
      unsigned pos = atomicAdd(&cnt[e], 1u);
      tokidx[e * 2048 + pos] = n;
      tokr[e * 2048 + pos] = r;
      s++;
    }
  }
  tslot[n] = s;
}

// ------- planner: dense chunk table (16 tokens per chunk, uniform expert) -----
__global__ void k_plan(const unsigned int* __restrict__ cnt,
    int* __restrict__ che, int* __restrict__ chb, int* __restrict__ nch) {
  if (threadIdx.x != 0 || blockIdx.x != 0) return;
  int ch = 0;
  for (int e = 0; e < NE; e++) {
    int c = (int)cnt[e];
    for (int b = 0; b < c && ch < CHMAX; b += 16) { che[ch] = e; chb[ch] = b; ch++; }
  }
  nch[0] = ch;
}

// ---------------- AG = A @ G (full sym G), AWb[e] = A_e . Wb ----------------
__global__ __launch_bounds__(256) void k_ag(const float* __restrict__ A,
    const float* __restrict__ G, const float* __restrict__ Wb,
    float* __restrict__ AG, float* __restrict__ AWb) {
  int e = blockIdx.x, c = threadIdx.x;
  float s = 0.f;
  for (int cp = 0; cp < C_; cp++) s = fmaf(A[e * C_ + cp], G[cp * C_ + c], s);
  AG[e * C_ + c] = s;
  float p = A[e * C_ + c] * Wb[c];
  __shared__ float red[256];
  red[c] = p;
  __syncthreads();
  for (int k = 128; k > 0; k >>= 1) {
    if (c < k) red[c] += red[c + k];
    __syncthreads();
  }
  if (c == 0) AWb[e] = red[0];
}

// ---------------- MA = M A^T, AGA = AG A^T (64x64 each) ----------------
__global__ __launch_bounds__(256) void k_small64(const float* __restrict__ M,
    const float* __restrict__ A, const float* __restrict__ AG,
    float* __restrict__ MA, float* __restrict__ AGA) {
  int e = blockIdx.x;
  int f = threadIdx.x >> 2, q = threadIdx.x & 3;
  float s1 = 0.f, s2 = 0.f;
  for (int c = q * 64; c < q * 64 + 64; c++) {
    float a = A[f * C_ + c];
    s1 = fmaf(M[e * C_ + c], a, s1);
    s2 = fmaf(AG[e * C_ + c], a, s2);
  }
  __shared__ float r1[256], r2[256];
  r1[threadIdx.x] = s1; r2[threadIdx.x] = s2;
  __syncthreads();
  if (q == 0) {
    MA[e * NE + f]  = r1[f*4] + r1[f*4+1] + r1[f*4+2] + r1[f*4+3];
    AGA[e * NE + f] = r2[f*4] + r2[f*4+1] + r2[f*4+2] + r2[f*4+3];
  }
}

// ------- cnew[e,d] = decay*c + alpha*(A_e.W_d + sumresp_e*b_d) -------
__global__ __launch_bounds__(256) void k_cnew(const float* __restrict__ A,
    const float* __restrict__ sumresp, const float* __restrict__ cen,
    const float* __restrict__ bmap, const float* __restrict__ W,
    float* __restrict__ cnew) {
  int d0 = blockIdx.x * 64;
  __shared__ float As[64][260];
  __shared__ float Ws[64][17];
  int t = threadIdx.x;
  for (int i = t; i < 16384; i += 256) As[i >> 8][i & 255] = A[i];
  int tx = t & 15, ty = t >> 4;
  int dd = t >> 2, k4 = (t & 3) * 4;
  float acc[4][4] = {};
  for (int c0 = 0; c0 < 256; c0 += 16) {
    float4 w4 = *(const float4*)&W[(size_t)(d0 + dd) * C_ + c0 + k4];
    __syncthreads();
    Ws[dd][k4] = w4.x; Ws[dd][k4+1] = w4.y; Ws[dd][k4+2] = w4.z; Ws[dd][k4+3] = w4.w;
    __syncthreads();
    #pragma unroll
    for (int k = 0; k < 16; k++) {
      float ra[4], rb[4];
      #pragma unroll
      for (int i = 0; i < 4; i++) ra[i] = As[ty*4 + i][c0 + k];
      #pragma unroll
      for (int j = 0; j < 4; j++) rb[j] = Ws[tx*4 + j][k];
      #pragma unroll
      for (int i = 0; i < 4; i++)
        #pragma unroll
        for (int j = 0; j < 4; j++)
          acc[i][j] = fmaf(ra[i], rb[j], acc[i][j]);
    }
  }
  #pragma unroll
  for (int i = 0; i < 4; i++) {
    int e = ty*4 + i;
    float sr = sumresp[e];
    #pragma unroll
    for (int j = 0; j < 4; j++) {
      int d = d0 + tx*4 + j;
      cnew[(size_t)e * D_ + d] = DECAYF * cen[(size_t)e * D_ + d]
                               + ALPHA * (acc[i][j] + sr * bmap[d]);
    }
  }
}

// ---------------- CC0 = cen cen^T ----------------
__global__ __launch_bounds__(256) void k_CC(const float* __restrict__ cen, float* __restrict__ CC0) {
  int d0 = blockIdx.x * 512;
  __shared__ float cs[64][17];
  int t = threadIdx.x;
  int tx = t & 15, ty = t >> 4;
  int ea = t >> 2, k4 = (t & 3) * 4;
  float acc[4][4] = {};
  for (int dk = 0; dk < 512; dk += 16) {
    float4 v = *(const float4*)&cen[(size_t)ea * D_ + d0 + dk + k4];
    __syncthreads();
    cs[ea][k4] = v.x; cs[ea][k4+1] = v.y; cs[ea][k4+2] = v.z; cs[ea][k4+3] = v.w;
    __syncthreads();
    #pragma unroll
    for (int k = 0; k < 16; k++) {
      float a_[4], b_[4];
      #pragma unroll
      for (int i = 0; i < 4; i++) a_[i] = cs[ty*4 + i][k];
      #pragma unroll
      for (int j = 0; j < 4; j++) b_[j] = cs[tx*4 + j][k];
      #pragma unroll
      for (int i = 0; i < 4; i++)
        #pragma unroll
        for (int j = 0; j < 4; j++)
          acc[i][j] = fmaf(a_[i], b_[j], acc[i][j]);
    }
  }
  #pragma unroll
  for (int i = 0; i < 4; i++)
    #pragma unroll
    for (int j = 0; j < 4; j++)
      atomicAdd(&CC0[(ty*4 + i) * NE + tx*4 + j], acc[i][j]);
}

// ---------------- out init with bias ----------------
__global__ __launch_bounds__(256) void k_bias(const float* __restrict__ pwB, float* __restrict__ out) {
  int idx = blockIdx.x * 256 + threadIdx.x;
  out[idx] = pwB[idx & 255];
}

// ------- stage A: dense grouped GEMM, 16 tok x 128 out per block -------
__global__ __launch_bounds__(256) void k_sA(const int* __restrict__ che,
    const int* __restrict__ chb, const int* __restrict__ nch,
    const unsigned int* __restrict__ cnt, const int* __restrict__ tokidx,
    const float* __restrict__ tokr, const int* __restrict__ tslot,
    const float* __restrict__ y, const float* __restrict__ cnew,
    float* __restrict__ out) {
  int nchv = nch[0];
  int i0 = blockIdx.y * 128;
  __shared__ int nsh[16]; __shared__ float rsh[16]; __shared__ int wsh[16];
  __shared__ float Ys[16][260];
  __shared__ float Bs[32][132];
  int t = threadIdx.x;
  for (int ch = blockIdx.x; ch < nchv; ch += SA_GRIDX) {
    int e = che[ch], base = chb[ch];
    int c = (int)cnt[e];
    __syncthreads();   // protect prior iteration's LDS reads
    if (t < 16) {
      int idx = base + t;
      if (idx < c) {
        int n = tokidx[e * 2048 + idx];
        nsh[t] = n; rsh[t] = tokr[e * 2048 + idx]; wsh[t] = tslot[n];
      } else { nsh[t] = 0; rsh[t] = 0.f; wsh[t] = 2; }
    }
    __syncthreads();
    {  // stage y rows
      int row = t >> 4, c0 = (t & 15) * 16;
      const float* yr = &y[nsh[row] * C_ + c0];
      float4 v0 = *(const float4*)&yr[0];
      float4 v1 = *(const float4*)&yr[4];
      float4 v2 = *(const float4*)&yr[8];
      float4 v3 = *(const float4*)&yr[12];
      *(float4*)&Ys[row][c0]      = v0;
      *(float4*)&Ys[row][c0 + 4]  = v1;
      *(float4*)&Ys[row][c0 + 8]  = v2;
      *(float4*)&Ys[row][c0 + 12] = v3;
    }
    int tx = t & 31, ty = t >> 5;
    int br = t >> 1, bk = (t & 1) * 16;
    float acc[2][4] = {};
    for (int k0 = 0; k0 < 256; k0 += 32) {
      const float* Brow = &cnew[(size_t)e * D_ + (size_t)(i0 + br) * C_ + k0 + bk];
      float4 b0 = *(const float4*)&Brow[0];
      float4 b1 = *(const float4*)&Brow[4];
      float4 b2 = *(const float4*)&Brow[8];
      float4 b3 = *(const float4*)&Brow[12];
      __syncthreads();
      Bs[bk+0][br]  = b0.x; Bs[bk+1][br]  = b0.y; Bs[bk+2][br]  = b0.z; Bs[bk+3][br]  = b0.w;
      Bs[bk+4][br]  = b1.x; Bs[bk+5][br]  = b1.y; Bs[bk+6][br]  = b1.z; Bs[bk+7][br]  = b1.w;
      Bs[bk+8][br]  = b2.x; Bs[bk+9][br]  = b2.y; Bs[bk+10][br] = b2.z; Bs[bk+11][br] = b2.w;
      Bs[bk+12][br] = b3.x; Bs[bk+13][br] = b3.y; Bs[bk+14][br] = b3.z; Bs[bk+15][br] = b3.w;
      __syncthreads();
      #pragma unroll
      for (int kk = 0; kk < 32; kk++) {
        float a0 = Ys[ty*2 + 0][k0 + kk];
        float a1 = Ys[ty*2 + 1][k0 + kk];
        float4 bv = *(const float4*)&Bs[kk][tx*4];
        acc[0][0] = fmaf(a0, bv.x, acc[0][0]); acc[0][1] = fmaf(a0, bv.y, acc[0][1]);
        acc[0][2] = fmaf(a0, bv.z, acc[0][2]); acc[0][3] = fmaf(a0, bv.w, acc[0][3]);
        acc[1][0] = fmaf(a1, bv.x, acc[1][0]); acc[1][1] = fmaf(a1, bv.y, acc[1][1]);
        acc[1][2] = fmaf(a1, bv.z, acc[1][2]); acc[1][3] = fmaf(a1, bv.w, acc[1][3]);
      }
    }
    #pragma unroll
    for (int i = 0; i < 2; i++) {
      int tk = ty*2 + i;
      float r = rsh[tk];
      if (r == 0.f) continue;
      int n = nsh[tk];
      float* op = &out[n * C_ + i0 + tx*4];
      if (wsh[tk] == 1) {
        float4 cur = *(const float4*)op;
        cur.x += r * acc[i][0]; cur.y += r * acc[i][1];
        cur.z += r * acc[i][2]; cur.w += r * acc[i][3];
        *(float4*)op = cur;
      } else {
        atomicAdd(op + 0, r * acc[i][0]);
        atomicAdd(op + 1, r * acc[i][1]);
        atomicAdd(op + 2, r * acc[i][2]);
        atomicAdd(op + 3, r * acc[i][3]);
      }
    }
  }
}

// ---------------- loss assembly ----------------
__global__ __launch_bounds__(256) void k_finalize(
    const float* __restrict__ S, const float* __restrict__ G,
    const float* __restrict__ M, const float* __restrict__ A,
    const float* __restrict__ AG, const float* __restrict__ CC0,
    const float* __restrict__ RR, const float* __restrict__ MA,
    const float* __restrict__ AGA, const float* __restrict__ Xsum,
    const float* __restrict__ Wb, const float* __restrict__ bb,
    const float* __restrict__ sr, const float* __restrict__ cb,
    const float* __restrict__ AWb, float* __restrict__ out) {
  int t = threadIdx.x;
  float a_gs = 0.f, a_am = 0.f, a_aag = 0.f;
  for (int i = t; i < 65536; i += 256) a_gs = fmaf(G[i], S[i], a_gs);
  for (int i = t; i < 16384; i += 256) {
    float a = A[i];
    a_am  = fmaf(M[i], a, a_am);
    a_aag = fmaf(AG[i], a, a_aag);
  }
  float a_cc = 0.f, a_ma = 0.f, a_aga = 0.f, a_cbsr = 0.f, a_awbsr = 0.f, a_srsr = 0.f;
  for (int p = t; p < 4096; p += 256) {
    float r = RR[p];
    int e = p >> 6, f = p & 63;
    float srf = sr[f];
    a_cc    = fmaf(r, CC0[p], a_cc);
    a_ma    = fmaf(r, MA[p], a_ma);
    a_aga   = fmaf(r, AGA[p], a_aga);
    a_cbsr  = fmaf(r * cb[e], srf, a_cbsr);
    a_awbsr = fmaf(r * AWb[e], srf, a_awbsr);
    a_srsr  = fmaf(r * sr[e], srf, a_srsr);
  }
  float a_xw = Xsum[t] * Wb[t];
  float a_srcb = 0.f, a_srawb = 0.f, a_sr2 = 0.f;
  if (t < 64) { float s = sr[t]; a_srcb = s * cb[t]; a_srawb = s * AWb[t]; a_sr2 = s * s; }
  float v[13] = {a_gs, a_am, a_aag, a_cc, a_ma, a_aga, a_cbsr, a_awbsr, a_srsr,
                 a_xw, a_srcb, a_srawb, a_sr2};
  __shared__ float red[256];
  __shared__ float tot[13];
  for (int q = 0; q < 13; q++) {
    red[t] = v[q];
    __syncthreads();
    for (int s2 = 128; s2 > 0; s2 >>= 1) {
      if (t < s2) red[t] += red[t + s2];
      __syncthreads();
    }
    if (t == 0) tot[q] = red[0];
    __syncthreads();
  }
  if (t == 0) {
    const float q = DECAYF, al = ALPHA;
    float bbv = bb[0];
    float sumkeyf2 = tot[0] + 2.f * tot[9] + 2048.f * bbv;
    float cross = q * (tot[1] + tot[10]) + al * (tot[2] + 2.f * tot[11] + bbv * tot[12]);
    float sumq2 = q*q * tot[3] + 2.f*q*al * (tot[4] + tot[6])
                + al*al * (tot[5] + 2.f * tot[7] + bbv * tot[8]);
    out[524288] = (0.25f / (2048.0f * 65536.0f)) * (sumkeyf2 - 2.f * cross + sumq2);
  }
}

extern "C" void kernel_launch(void* const* d_in, const int* in_sizes, int n_in,
                              void* d_out, int out_size, void* d_ws, size_t ws_size,
                              hipStream_t stream) {
  const float* x    = (const float*)d_in[0];
  const float* u    = (const float*)d_in[1];
  const float* Wm   = (const float*)d_in[2];
  const float* bmap = (const float*)d_in[3];
  const float* pw   = (const float*)d_in[4];
  const float* pwB  = (const float*)d_in[5];
  const float* cen  = (const float*)d_in[6];
  float* out = (float*)d_out;
  float* ws  = (float*)d_ws;

  float* S_      = ws + OFF_S;
  float* Xsum    = ws + OFF_XSUM;
  float* G       = ws + OFF_G;
  float* M       = ws + OFF_M;
  float* Wb      = ws + OFF_WB;
  float* bb      = ws + OFF_BB;
  float* sumresp = ws + OFF_SUMR;
  float* A       = ws + OFF_A;
  float* CC0     = ws + OFF_CC0;
  float* RR      = ws + OFF_RR;
  unsigned int* cnt = (unsigned int*)(ws + OFF_CNT);
  float* cn2     = ws + OFF_CN2;
  float* cb      = ws + OFF_CB;
  int*   tslot   = (int*)(ws + OFF_TSLOT);
  float* resp    = ws + OFF_RESP;
  float* AG      = ws + OFF_AG;
  float* MA      = ws + OFF_MA;
  float* AGA     = ws + OFF_AGA;
  float* AWb     = ws + OFF_AWB;
  int*   che     = (int*)(ws + OFF_CHE);
  int*   chb     = (int*)(ws + OFF_CHB);
  int*   nch     = (int*)(ws + OFF_NCH);
  float* y       = ws + OFF_Y;
  float* cnew    = ws + OFF_CNEW;
  int*   tokidx  = (int*)(ws + OFF_TIDX);
  float* tokr    = ws + OFF_TOKR;

  hipMemsetAsync(d_ws, 0, ZFLOATS * sizeof(float), stream);

  k_cstats<<<256, 256, 0, stream>>>(cen, bmap, cn2, cb);
  k_bb<<<1, 256, 0, stream>>>(bmap, bb);
  k_S<<<dim3(8, 16), 256, 0, stream>>>(x, S_);
  k_xsum<<<32, 256, 0, stream>>>(x, Xsum);
  k_G<<<dim3(64, 10), 256, 0, stream>>>(Wm, G);
  k_mirror<<<96, 256, 0, stream>>>(G);
  k_CC<<<128, 256, 0, stream>>>(cen, CC0);
  k_mm64<<<dim3(128, 4), 256, 0, stream>>>(cen, Wm, M);
  k_Wb<<<256, 256, 0, stream>>>(bmap, Wm, Wb);
  k_y<<<dim3(32, 4), 256, 0, stream>>>(x, pw, y);
  k_resp<<<2048, 64, 0, stream>>>(x, u, M, cn2, cb, resp);
  k_route<<<8, 256, 0, stream>>>(resp, cnt, tokidx, tokr, tslot);
  k_A2<<<dim3(8, 4), 256, 0, stream>>>(resp, x, A);
  k_sr<<<8, 256, 0, stream>>>(resp, sumresp);
  k_RR2<<<8, 256, 0, stream>>>(resp, RR);
  k_plan<<<1, 64, 0, stream>>>(cnt, che, chb, nch);
  k_ag<<<64, 256, 0, stream>>>(A, G, Wb, AG, AWb);
  k_small64<<<64, 256, 0, stream>>>(M, A, AG, MA, AGA);
  k_cnew<<<1024, 256, 0, stream>>>(A, sumresp, cen, bmap, Wm, cnew);
  k_bias<<<2048, 256, 0, stream>>>(pwB, out);
  k_sA<<<dim3(SA_GRIDX, 2), 256, 0, stream>>>(che, chb, nch, cnt, tokidx, tokr,
                                              tslot, y, cnew, out);
  k_finalize<<<1, 256, 0, stream>>>(S_, G, M, A, AG, CC0, RR, MA, AGA, Xsum, Wb,
                                    bb, sumresp, cb, AWb, out);
}

// Round 6
// 612.053 us; speedup vs baseline: 2.0431x; 1.2109x over previous
//
#include <hip/hip_runtime.h>

// Problem dims
constexpr int N_TOK = 2048;   // T*B
constexpr int C_    = 256;    // in features (== R == OUT)
constexpr int NE    = 64;     // experts
constexpr int D_    = 65536;  // R*OUT centroid dim
constexpr float DECAYF = 0.999f;
constexpr float OMD    = 0.001f;
constexpr float ALPHA  = OMD / 2048.0f;   // (1-decay)/N
constexpr float RTHRESH = 1e-5f;
constexpr int CHMAX = 8448;
constexpr int SA_GRIDX = 512;

// ---------- workspace layout (float offsets) ----------
constexpr size_t OFF_S     = 0;        // 65536  S = X^T X (full)
constexpr size_t OFF_XSUM  = 65536;    // 256
constexpr size_t OFF_G     = 65792;    // 65536  G = W^T W (full, assembled by k_Gred)
constexpr size_t OFF_M     = 131328;   // 16384  M = cen @ W
constexpr size_t OFF_WB    = 147712;   // 256    Wb = b^T W
constexpr size_t OFF_BB    = 147968;   // 16     bb[0] = ||b||^2 ; bb[1] = gsum (G.S)
constexpr size_t OFF_SUMR  = 147984;   // 64     sum_n resp
constexpr size_t OFF_A     = 148048;   // 16384  A = resp^T X
constexpr size_t OFF_CC0   = 164432;   // 4096   cen cen^T
constexpr size_t OFF_RR    = 168528;   // 4096   resp^T resp
constexpr size_t OFF_CNT   = 172624;   // 64     per-expert token counts (uint)
constexpr size_t OFF_CN2   = 172688;   // 64
constexpr size_t OFF_CB    = 172752;   // 64
constexpr size_t OFF_TSLOT = 172816;   // 2048   per-token writer count (int)
constexpr size_t ZFLOATS   = 174864;
// overwritten-before-read zone:
constexpr size_t OFF_RESP  = 174864;   // 131072
constexpr size_t OFF_AG    = 174864;   // 16384 (overlay after resp dead)
constexpr size_t OFF_MA    = 191248;   // 4096
constexpr size_t OFF_AGA   = 195344;   // 4096
constexpr size_t OFF_AWB   = 199440;   // 64
constexpr size_t OFF_CHE   = 199504;   // 8448
constexpr size_t OFF_CHB   = 207952;   // 8448
constexpr size_t OFF_NCH   = 216400;   // 16
constexpr size_t OFF_Y     = 305936;   // 524288 y = X @ pw^T
constexpr size_t OFF_CNEW  = 830224;   // 4194304 ; ALSO reused (before k_cnew) as
                                       //   k_G partials (3*64*16384=3.15M floats) then
                                       //   k_M partials (128*16384=2.10M floats)
constexpr size_t OFF_TIDX  = 5024528;  // 131072 (int)
constexpr size_t OFF_TOKR  = 5155600;  // 131072
// total 5286672 floats = 21,146,688 bytes

// ------- centroid stats: cn2[e], cb[e] -------
__global__ __launch_bounds__(256) void k_cstats(const float* __restrict__ cen,
    const float* __restrict__ bmap, float* __restrict__ cn2, float* __restrict__ cb) {
  int e = blockIdx.x >> 2;
  int d0 = (blockIdx.x & 3) * 16384;
  const float* ce = cen + (size_t)e * D_ + d0;
  const float* bm = bmap + d0;
  float s2 = 0.f, sb = 0.f;
  for (int d = threadIdx.x; d < 16384; d += 256) {
    float v = ce[d];
    s2 = fmaf(v, v, s2);
    sb = fmaf(v, bm[d], sb);
  }
  __shared__ float r0[256], r1[256];
  r0[threadIdx.x] = s2; r1[threadIdx.x] = sb;
  __syncthreads();
  for (int s = 128; s > 0; s >>= 1) {
    if (threadIdx.x < s) { r0[threadIdx.x] += r0[threadIdx.x + s];
                           r1[threadIdx.x] += r1[threadIdx.x + s]; }
    __syncthreads();
  }
  if (threadIdx.x == 0) { atomicAdd(&cn2[e], r0[0]); atomicAdd(&cb[e], r1[0]); }
}

// ---------------- bb[0] = ||b||^2 (4 blocks, atomic) ----------------
__global__ __launch_bounds__(256) void k_bb(const float* __restrict__ bmap, float* __restrict__ bb) {
  int base = blockIdx.x * 16384 + threadIdx.x;
  float s = 0.f;
  for (int q = 0; q < 64; q++) { float v = bmap[base + q * 256]; s = fmaf(v, v, s); }
  __shared__ float red[256];
  red[threadIdx.x] = s;
  __syncthreads();
  for (int k = 128; k > 0; k >>= 1) {
    if (threadIdx.x < k) red[threadIdx.x] += red[threadIdx.x + k];
    __syncthreads();
  }
  if (threadIdx.x == 0) atomicAdd(&bb[0], red[0]);
}

// ======== generic 64x64 gram-style tile (kept for S / A2 / RR2) ========
template<int KCHUNK>
__device__ __forceinline__ void gemm_tt_tile(
    const float* __restrict__ Aop, int lda, int ca,
    const float* __restrict__ Bop, int ldb, int cb,
    int d0, float* __restrict__ Out, int ldo, int ro, int co) {
  __shared__ float Wa[32][68], Wb[32][68];
  int t = threadIdx.x;
  int tx = t & 15, ty = t >> 4;
  int lr = t >> 3, lc = (t & 7) * 8;
  float acc[4][4] = {};
  for (int dk = 0; dk < KCHUNK; dk += 32) {
    const float* Arow = &Aop[(size_t)(d0 + dk + lr) * lda + ca];
    const float* Brow = &Bop[(size_t)(d0 + dk + lr) * ldb + cb];
    float4 a0 = *(const float4*)&Arow[lc];
    float4 a1 = *(const float4*)&Arow[lc + 4];
    float4 b0 = *(const float4*)&Brow[lc];
    float4 b1 = *(const float4*)&Brow[lc + 4];
    __syncthreads();
    *(float4*)&Wa[lr][lc]     = a0;
    *(float4*)&Wa[lr][lc + 4] = a1;
    *(float4*)&Wb[lr][lc]     = b0;
    *(float4*)&Wb[lr][lc + 4] = b1;
    __syncthreads();
    #pragma unroll
    for (int k = 0; k < 32; k++) {
      float4 ra4 = *(const float4*)&Wa[k][ty * 4];
      float4 rb4 = *(const float4*)&Wb[k][tx * 4];
      float ra[4] = {ra4.x, ra4.y, ra4.z, ra4.w};
      float rb[4] = {rb4.x, rb4.y, rb4.z, rb4.w};
      #pragma unroll
      for (int i = 0; i < 4; i++)
        #pragma unroll
        for (int j = 0; j < 4; j++)
          acc[i][j] = fmaf(ra[i], rb[j], acc[i][j]);
    }
  }
  #pragma unroll
  for (int i = 0; i < 4; i++)
    #pragma unroll
    for (int j = 0; j < 4; j++)
      atomicAdd(&Out[(size_t)(ro + ty * 4 + i) * ldo + co + tx * 4 + j], acc[i][j]);
}

// ---- G = W^T W: 128x128 tiles, pairs {(0,0),(0,1),(1,1)}, ksplit 64, NO atomics:
// partials into spare cnew region. Thread-tile 8x8 = 4x(4x4) split quadrants ->
// all frag reads are 16B-stride b128 (2-way, free). 1 B/MAC LDS traffic.
__global__ __launch_bounds__(256) void k_G(const float* __restrict__ W,
    float* __restrict__ part) {
  const int tit[3] = {0, 0, 1}, tjt[3] = {0, 1, 1};
  int p = blockIdx.y;
  int c1 = tit[p] * 128, c2 = tjt[p] * 128;
  int d0 = blockIdx.x * 1024;
  __shared__ float Wa[32][132], Wb[32][132];
  int t = threadIdx.x;
  int tx = t & 15, ty = t >> 4;
  int lr = t >> 3, lc = (t & 7) * 16;
  float acc[2][2][4][4] = {};
  for (int dk = 0; dk < 1024; dk += 32) {
    const float* Wr = &W[(size_t)(d0 + dk + lr) * C_];
    float4 a0 = *(const float4*)&Wr[c1 + lc];
    float4 a1 = *(const float4*)&Wr[c1 + lc + 4];
    float4 a2 = *(const float4*)&Wr[c1 + lc + 8];
    float4 a3 = *(const float4*)&Wr[c1 + lc + 12];
    float4 b0 = *(const float4*)&Wr[c2 + lc];
    float4 b1 = *(const float4*)&Wr[c2 + lc + 4];
    float4 b2 = *(const float4*)&Wr[c2 + lc + 8];
    float4 b3 = *(const float4*)&Wr[c2 + lc + 12];
    __syncthreads();
    *(float4*)&Wa[lr][lc]      = a0;
    *(float4*)&Wa[lr][lc + 4]  = a1;
    *(float4*)&Wa[lr][lc + 8]  = a2;
    *(float4*)&Wa[lr][lc + 12] = a3;
    *(float4*)&Wb[lr][lc]      = b0;
    *(float4*)&Wb[lr][lc + 4]  = b1;
    *(float4*)&Wb[lr][lc + 8]  = b2;
    *(float4*)&Wb[lr][lc + 12] = b3;
    __syncthreads();
    #pragma unroll 8
    for (int k = 0; k < 32; k++) {
      float4 ra0 = *(const float4*)&Wa[k][ty * 4];
      float4 ra1 = *(const float4*)&Wa[k][64 + ty * 4];
      float4 rb0 = *(const float4*)&Wb[k][tx * 4];
      float4 rb1 = *(const float4*)&Wb[k][64 + tx * 4];
      float A0[4] = {ra0.x, ra0.y, ra0.z, ra0.w};
      float A1[4] = {ra1.x, ra1.y, ra1.z, ra1.w};
      float B0[4] = {rb0.x, rb0.y, rb0.z, rb0.w};
      float B1[4] = {rb1.x, rb1.y, rb1.z, rb1.w};
      #pragma unroll
      for (int i = 0; i < 4; i++)
        #pragma unroll
        for (int j = 0; j < 4; j++) {
          acc[0][0][i][j] = fmaf(A0[i], B0[j], acc[0][0][i][j]);
          acc[0][1][i][j] = fmaf(A0[i], B1[j], acc[0][1][i][j]);
          acc[1][0][i][j] = fmaf(A1[i], B0[j], acc[1][0][i][j]);
          acc[1][1][i][j] = fmaf(A1[i], B1[j], acc[1][1][i][j]);
        }
    }
  }
  float* pp = &part[((size_t)p * 64 + blockIdx.x) * 16384];
  #pragma unroll
  for (int qi = 0; qi < 2; qi++)
    #pragma unroll
    for (int qj = 0; qj < 2; qj++)
      #pragma unroll
      for (int i = 0; i < 4; i++)
        *(float4*)&pp[(qi * 64 + ty * 4 + i) * 128 + qj * 64 + tx * 4] =
            *(float4*)&acc[qi][qj][i][0];
}

// ---- reduce 64 k-partials -> full G (mirror fused for off-diagonal pair) ----
__global__ __launch_bounds__(256) void k_Gred(const float* __restrict__ part,
    float* __restrict__ G) {
  const int tit[3] = {0, 0, 1}, tjt[3] = {0, 1, 1};
  int p = blockIdx.y;
  int i = blockIdx.x * 256 + threadIdx.x;   // 0..16383
  const float* base = part + (size_t)p * 64 * 16384 + i;
  float s = 0.f;
  for (int kb = 0; kb < 64; kb++) s += base[(size_t)kb * 16384];
  int r = i >> 7, c = i & 127;
  int r0 = tit[p] * 128 + r, c0 = tjt[p] * 128 + c;
  G[r0 * C_ + c0] = s;
  if (p == 1) G[c0 * C_ + r0] = s;
}

// ---- S = X^T X: full 16 tile pairs, ksplit 8x256 ----
__global__ __launch_bounds__(256) void k_S(const float* __restrict__ x, float* __restrict__ S) {
  int p = blockIdx.y;
  int ti = p >> 2, tj = p & 3;
  gemm_tt_tile<256>(x, C_, ti * 64, x, C_, tj * 64, blockIdx.x * 256,
                    S, C_, ti * 64, tj * 64);
}

// ---- A = resp^T X ----
__global__ __launch_bounds__(256) void k_A2(const float* __restrict__ resp,
    const float* __restrict__ x, float* __restrict__ A) {
  gemm_tt_tile<256>(resp, NE, 0, x, C_, blockIdx.y * 64, blockIdx.x * 256,
                    A, C_, 0, blockIdx.y * 64);
}

// ---- RR = resp^T resp ----
__global__ __launch_bounds__(256) void k_RR2(const float* __restrict__ resp,
    float* __restrict__ RR) {
  gemm_tt_tile<256>(resp, NE, 0, resp, NE, 0, blockIdx.x * 256, RR, NE, 0, 0);
}

// ---- sumresp ----
__global__ __launch_bounds__(256) void k_sr(const float* __restrict__ resp,
    float* __restrict__ sumresp) {
  int e = threadIdx.x & 63, part = threadIdx.x >> 6;
  int n0 = blockIdx.x * 256 + part * 64;
  float s = 0.f;
  for (int n = n0; n < n0 + 64; n++) s += resp[n * NE + e];
  __shared__ float red[256];
  red[threadIdx.x] = s;
  __syncthreads();
  if (part == 0)
    atomicAdd(&sumresp[e], red[e] + red[64 + e] + red[128 + e] + red[192 + e]);
}

// ---------------- Xsum ----------------
__global__ __launch_bounds__(256) void k_xsum(const float* __restrict__ x, float* __restrict__ xsum) {
  int n0 = blockIdx.x * 64;
  int c = threadIdx.x;
  float s = 0.f;
  for (int n = 0; n < 64; n++) s += x[(n0 + n) * C_ + c];
  atomicAdd(&xsum[c], s);
}

// ---- M = cen @ W (fp32, precision-critical for logits). 64e x 64c tile,
// ksplit 128x512, partials (no 128-way atomics). cen staged TRANSPOSED in LDS
// so both frag reads are b128. ----
__global__ __launch_bounds__(256) void k_M(const float* __restrict__ cen,
    const float* __restrict__ W, float* __restrict__ mpart) {
  int kb = blockIdx.x;           // d-chunk of 512
  int c0 = blockIdx.y * 64;
  int d0 = kb * 512;
  __shared__ float As[32][68];   // [d][e] transposed cen
  __shared__ float Bs[32][68];   // [d][c] straight W
  int t = threadIdx.x;
  int tx = t & 15, ty = t >> 4;
  int e = t >> 2, dg = t & 3;        // cen load map
  int lr = t >> 3, lc = (t & 7) * 8; // W load map
  float acc[4][4] = {};
  for (int dk = 0; dk < 512; dk += 32) {
    const float* cr = &cen[(size_t)e * D_ + d0 + dk];
    float4 cv0 = *(const float4*)&cr[dg * 4];
    float4 cv1 = *(const float4*)&cr[16 + dg * 4];
    const float* wr = &W[(size_t)(d0 + dk + lr) * C_ + c0];
    float4 w0 = *(const float4*)&wr[lc];
    float4 w1 = *(const float4*)&wr[lc + 4];
    __syncthreads();
    As[dg * 4 + 0][e] = cv0.x; As[dg * 4 + 1][e] = cv0.y;
    As[dg * 4 + 2][e] = cv0.z; As[dg * 4 + 3][e] = cv0.w;
    As[16 + dg * 4 + 0][e] = cv1.x; As[16 + dg * 4 + 1][e] = cv1.y;
    As[16 + dg * 4 + 2][e] = cv1.z; As[16 + dg * 4 + 3][e] = cv1.w;
    *(float4*)&Bs[lr][lc]     = w0;
    *(float4*)&Bs[lr][lc + 4] = w1;
    __syncthreads();
    #pragma unroll 8
    for (int k = 0; k < 32; k++) {
      float4 ra4 = *(const float4*)&As[k][ty * 4];
      float4 rb4 = *(const float4*)&Bs[k][tx * 4];
      float ra[4] = {ra4.x, ra4.y, ra4.z, ra4.w};
      float rb[4] = {rb4.x, rb4.y, rb4.z, rb4.w};
      #pragma unroll
      for (int i = 0; i < 4; i++)
        #pragma unroll
        for (int j = 0; j < 4; j++)
          acc[i][j] = fmaf(ra[i], rb[j], acc[i][j]);
    }
  }
  float* pp = &mpart[(size_t)kb * 16384];
  #pragma unroll
  for (int i = 0; i < 4; i++)
    *(float4*)&pp[(ty * 4 + i) * C_ + c0 + tx * 4] = *(float4*)&acc[i][0];
}

// ---- reduce 128 k-partials -> M ----
__global__ __launch_bounds__(256) void k_Mred(const float* __restrict__ mpart,
    float* __restrict__ M) {
  int i = blockIdx.x * 256 + threadIdx.x;   // 0..16383
  float s = 0.f;
  for (int kb = 0; kb < 128; kb++) s += mpart[(size_t)kb * 16384 + i];
  M[i] = s;
}

// ---------------- Wb[c] = sum_d b[d] W[d,c] (skip all-zero b chunks) ----------
__global__ __launch_bounds__(256) void k_Wb(const float* __restrict__ bmap,
    const float* __restrict__ W, float* __restrict__ Wb) {
  int d0 = blockIdx.x * 256;
  int c = threadIdx.x;
  __shared__ float bs[256];
  __shared__ int any;
  if (c == 0) any = 0;
  __syncthreads();
  float bv = bmap[d0 + c];
  bs[c] = bv;
  if (bv != 0.f) any = 1;
  __syncthreads();
  if (any == 0) return;
  float s = 0.f;
  for (int d = 0; d < 256; d++) s = fmaf(bs[d], W[(size_t)(d0 + d) * C_ + c], s);
  atomicAdd(&Wb[c], s);
}

// ---------------- y = X @ pw^T ----------------
__global__ __launch_bounds__(256) void k_y(const float* __restrict__ x,
    const float* __restrict__ pw, float* __restrict__ y) {
  int n0 = blockIdx.x * 64, k0 = blockIdx.y * 64;
  __shared__ float Xs[64][17], Ps[64][17];
  int t = threadIdx.x;
  int tx = t & 15, ty = t >> 4;
  int r = t >> 2, q4 = (t & 3) * 4;
  float acc[4][4] = {};
  for (int j0 = 0; j0 < 256; j0 += 16) {
    float4 va = *(const float4*)&x[(n0 + r) * C_ + j0 + q4];
    float4 vb = *(const float4*)&pw[(k0 + r) * C_ + j0 + q4];
    __syncthreads();
    Xs[r][q4] = va.x; Xs[r][q4+1] = va.y; Xs[r][q4+2] = va.z; Xs[r][q4+3] = va.w;
    Ps[r][q4] = vb.x; Ps[r][q4+1] = vb.y; Ps[r][q4+2] = vb.z; Ps[r][q4+3] = vb.w;
    __syncthreads();
    #pragma unroll
    for (int k = 0; k < 16; k++) {
      float ra[4], rb[4];
      #pragma unroll
      for (int i = 0; i < 4; i++) ra[i] = Xs[ty*4 + i][k];
      #pragma unroll
      for (int j = 0; j < 4; j++) rb[j] = Ps[tx*4 + j][k];
      #pragma unroll
      for (int i = 0; i < 4; i++)
        #pragma unroll
        for (int j = 0; j < 4; j++)
          acc[i][j] = fmaf(ra[i], rb[j], acc[i][j]);
    }
  }
  #pragma unroll
  for (int i = 0; i < 4; i++)
    #pragma unroll
    for (int j = 0; j < 4; j++)
      y[(n0 + ty*4 + i) * C_ + k0 + tx*4 + j] = acc[i][j];
}

// ------- resp softmax --------
__global__ __launch_bounds__(64) void k_resp(const float* __restrict__ x,
    const float* __restrict__ u, const float* __restrict__ M,
    const float* __restrict__ cn2, const float* __restrict__ cb,
    float* __restrict__ resp) {
  int n = blockIdx.x;
  int e = threadIdx.x;
  __shared__ float xs[256];
  *(float4*)&xs[e * 4] = *(const float4*)&x[n * C_ + e * 4];
  __syncthreads();
  const float* Me = M + e * C_;
  float s = 0.f;
  #pragma unroll 8
  for (int j = 0; j < 256; j += 4) {
    float4 m4 = *(const float4*)&Me[j];
    s = fmaf(xs[j],   m4.x, s);
    s = fmaf(xs[j+1], m4.y, s);
    s = fmaf(xs[j+2], m4.z, s);
    s = fmaf(xs[j+3], m4.w, s);
  }
  float uu = u[n * NE + e];
  float g = -logf(-logf(uu));
  float logit = 2.0f * (s + cb[e]) - cn2[e] + g;   // TAU == 1
  float m = logit;
  for (int off = 32; off > 0; off >>= 1) m = fmaxf(m, __shfl_xor(m, off));
  float ex = expf(logit - m);
  float sum = ex;
  for (int off = 32; off > 0; off >>= 1) sum += __shfl_xor(sum, off);
  resp[n * NE + e] = ex / sum;
}

// ------- routing (NO cap — r3 lesson) -------
__global__ __launch_bounds__(256) void k_route(const float* __restrict__ resp,
    unsigned int* __restrict__ cnt, int* __restrict__ tokidx,
    float* __restrict__ tokr, int* __restrict__ tslot) {
  int n = blockIdx.x * 256 + threadIdx.x;
  int s = 0;
  #pragma unroll 4
  for (int e = 0; e < NE; e++) {
    float r = resp[n * NE + e];
    if (r > RTHRESH) {
      unsigned pos = atomicAdd(&cnt[e], 1u);
      tokidx[e * 2048 + pos] = n;
      tokr[e * 2048 + pos] = r;
      s++;
    }
  }
  tslot[n] = s;
}

// ------- planner -------
__global__ void k_plan(const unsigned int* __restrict__ cnt,
    int* __restrict__ che, int* __restrict__ chb, int* __restrict__ nch) {
  if (threadIdx.x != 0 || blockIdx.x != 0) return;
  int ch = 0;
  for (int e = 0; e < NE; e++) {
    int c = (int)cnt[e];
    for (int b = 0; b < c && ch < CHMAX; b += 16) { che[ch] = e; chb[ch] = b; ch++; }
  }
  nch[0] = ch;
}

// ---------------- AG = A @ G, AWb ----------------
__global__ __launch_bounds__(256) void k_ag(const float* __restrict__ A,
    const float* __restrict__ G, const float* __restrict__ Wb,
    float* __restrict__ AG, float* __restrict__ AWb) {
  int e = blockIdx.x, c = threadIdx.x;
  float s = 0.f;
  for (int cp = 0; cp < C_; cp++) s = fmaf(A[e * C_ + cp], G[cp * C_ + c], s);
  AG[e * C_ + c] = s;
  float p = A[e * C_ + c] * Wb[c];
  __shared__ float red[256];
  red[c] = p;
  __syncthreads();
  for (int k = 128; k > 0; k >>= 1) {
    if (c < k) red[c] += red[c + k];
    __syncthreads();
  }
  if (c == 0) AWb[e] = red[0];
}

// ---------------- MA = M A^T, AGA = AG A^T ----------------
__global__ __launch_bounds__(256) void k_small64(const float* __restrict__ M,
    const float* __restrict__ A, const float* __restrict__ AG,
    float* __restrict__ MA, float* __restrict__ AGA) {
  int e = blockIdx.x;
  int f = threadIdx.x >> 2, q = threadIdx.x & 3;
  float s1 = 0.f, s2 = 0.f;
  for (int c = q * 64; c < q * 64 + 64; c++) {
    float a = A[f * C_ + c];
    s1 = fmaf(M[e * C_ + c], a, s1);
    s2 = fmaf(AG[e * C_ + c], a, s2);
  }
  __shared__ float r1[256], r2[256];
  r1[threadIdx.x] = s1; r2[threadIdx.x] = s2;
  __syncthreads();
  if (q == 0) {
    MA[e * NE + f]  = r1[f*4] + r1[f*4+1] + r1[f*4+2] + r1[f*4+3];
    AGA[e * NE + f] = r2[f*4] + r2[f*4+1] + r2[f*4+2] + r2[f*4+3];
  }
}

// ------- cnew[e,d] = decay*cen + alpha*(A_e.W_d + sr_e*b_d) -------
// 64e x 128d tile, thread 4e x (4+4)d split-quadrant; A and W-chunk staged
// transposed in LDS so all frag reads are b128 (2-way max). 1.5 B/MAC.
__global__ __launch_bounds__(256) void k_cnew(const float* __restrict__ A,
    const float* __restrict__ sumresp, const float* __restrict__ cen,
    const float* __restrict__ bmap, const float* __restrict__ W,
    float* __restrict__ cnew) {
  int d0 = blockIdx.x * 128;
  __shared__ float As[32][68];    // [c][e]
  __shared__ float Bs[32][132];   // [c][d]
  int t = threadIdx.x;
  int tx = t & 15, ty = t >> 4;
  int e = t >> 2, cg = t & 3;     // A load map
  int dd = t >> 1, ch = (t & 1) * 16;  // W load map
  float acc[4][2][4] = {};
  for (int c0 = 0; c0 < 256; c0 += 32) {
    const float* ar = &A[e * C_ + c0];
    float4 a0 = *(const float4*)&ar[cg * 4];
    float4 a1 = *(const float4*)&ar[16 + cg * 4];
    const float* wr = &W[(size_t)(d0 + dd) * C_ + c0 + ch];
    float4 w0 = *(const float4*)&wr[0];
    float4 w1 = *(const float4*)&wr[4];
    float4 w2 = *(const float4*)&wr[8];
    float4 w3 = *(const float4*)&wr[12];
    __syncthreads();
    As[cg * 4 + 0][e] = a0.x; As[cg * 4 + 1][e] = a0.y;
    As[cg * 4 + 2][e] = a0.z; As[cg * 4 + 3][e] = a0.w;
    As[16 + cg * 4 + 0][e] = a1.x; As[16 + cg * 4 + 1][e] = a1.y;
    As[16 + cg * 4 + 2][e] = a1.z; As[16 + cg * 4 + 3][e] = a1.w;
    Bs[ch + 0][dd] = w0.x;  Bs[ch + 1][dd] = w0.y;
    Bs[ch + 2][dd] = w0.z;  Bs[ch + 3][dd] = w0.w;
    Bs[ch + 4][dd] = w1.x;  Bs[ch + 5][dd] = w1.y;
    Bs[ch + 6][dd] = w1.z;  Bs[ch + 7][dd] = w1.w;
    Bs[ch + 8][dd] = w2.x;  Bs[ch + 9][dd] = w2.y;
    Bs[ch + 10][dd] = w2.z; Bs[ch + 11][dd] = w2.w;
    Bs[ch + 12][dd] = w3.x; Bs[ch + 13][dd] = w3.y;
    Bs[ch + 14][dd] = w3.z; Bs[ch + 15][dd] = w3.w;
    __syncthreads();
    #pragma unroll 8
    for (int k = 0; k < 32; k++) {
      float4 ra4 = *(const float4*)&As[k][ty * 4];
      float4 rb0 = *(const float4*)&Bs[k][tx * 4];
      float4 rb1 = *(const float4*)&Bs[k][64 + tx * 4];
      float ra[4] = {ra4.x, ra4.y, ra4.z, ra4.w};
      float b0[4] = {rb0.x, rb0.y, rb0.z, rb0.w};
      float b1[4] = {rb1.x, rb1.y, rb1.z, rb1.w};
      #pragma unroll
      for (int i = 0; i < 4; i++)
        #pragma unroll
        for (int j = 0; j < 4; j++) {
          acc[i][0][j] = fmaf(ra[i], b0[j], acc[i][0][j]);
          acc[i][1][j] = fmaf(ra[i], b1[j], acc[i][1][j]);
        }
    }
  }
  #pragma unroll
  for (int i = 0; i < 4; i++) {
    int ee = ty * 4 + i;
    float sr = sumresp[ee];
    #pragma unroll
    for (int q = 0; q < 2; q++) {
      int d = d0 + q * 64 + tx * 4;
      float4 cv = *(const float4*)&cen[(size_t)ee * D_ + d];
      float4 bv = *(const float4*)&bmap[d];
      float4 o;
      o.x = DECAYF * cv.x + ALPHA * (acc[i][q][0] + sr * bv.x);
      o.y = DECAYF * cv.y + ALPHA * (acc[i][q][1] + sr * bv.y);
      o.z = DECAYF * cv.z + ALPHA * (acc[i][q][2] + sr * bv.z);
      o.w = DECAYF * cv.w + ALPHA * (acc[i][q][3] + sr * bv.w);
      *(float4*)&cnew[(size_t)ee * D_ + d] = o;
    }
  }
}

// ---------------- CC0 = cen cen^T ----------------
__global__ __launch_bounds__(256) void k_CC(const float* __restrict__ cen, float* __restrict__ CC0) {
  int d0 = blockIdx.x * 512;
  __shared__ float cs[64][17];
  int t = threadIdx.x;
  int tx = t & 15, ty = t >> 4;
  int ea = t >> 2, k4 = (t & 3) * 4;
  float acc[4][4] = {};
  for (int dk = 0; dk < 512; dk += 16) {
    float4 v = *(const float4*)&cen[(size_t)ea * D_ + d0 + dk + k4];
    __syncthreads();
    cs[ea][k4] = v.x; cs[ea][k4+1] = v.y; cs[ea][k4+2] = v.z; cs[ea][k4+3] = v.w;
    __syncthreads();
    #pragma unroll
    for (int k = 0; k < 16; k++) {
      float a_[4], b_[4];
      #pragma unroll
      for (int i = 0; i < 4; i++) a_[i] = cs[ty*4 + i][k];
      #pragma unroll
      for (int j = 0; j < 4; j++) b_[j] = cs[tx*4 + j][k];
      #pragma unroll
      for (int i = 0; i < 4; i++)
        #pragma unroll
        for (int j = 0; j < 4; j++)
          acc[i][j] = fmaf(a_[i], b_[j], acc[i][j]);
    }
  }
  #pragma unroll
  for (int i = 0; i < 4; i++)
    #pragma unroll
    for (int j = 0; j < 4; j++)
      atomicAdd(&CC0[(ty*4 + i) * NE + tx*4 + j], acc[i][j]);
}

// ---------------- out init with bias ----------------
__global__ __launch_bounds__(256) void k_bias(const float* __restrict__ pwB, float* __restrict__ out) {
  int idx = blockIdx.x * 256 + threadIdx.x;
  out[idx] = pwB[idx & 255];
}

// ------- stage A: dense grouped GEMM -------
__global__ __launch_bounds__(256) void k_sA(const int* __restrict__ che,
    const int* __restrict__ chb, const int* __restrict__ nch,
    const unsigned int* __restrict__ cnt, const int* __restrict__ tokidx,
    const float* __restrict__ tokr, const int* __restrict__ tslot,
    const float* __restrict__ y, const float* __restrict__ cnew,
    float* __restrict__ out) {
  int nchv = nch[0];
  int i0 = blockIdx.y * 128;
  __shared__ int nsh[16]; __shared__ float rsh[16]; __shared__ int wsh[16];
  __shared__ float Ys[16][260];
  __shared__ float Bs[32][132];
  int t = threadIdx.x;
  for (int ch = blockIdx.x; ch < nchv; ch += SA_GRIDX) {
    int e = che[ch], base = chb[ch];
    int c = (int)cnt[e];
    __syncthreads();
    if (t < 16) {
      int idx = base + t;
      if (idx < c) {
        int n = tokidx[e * 2048 + idx];
        nsh[t] = n; rsh[t] = tokr[e * 2048 + idx]; wsh[t] = tslot[n];
      } else { nsh[t] = 0; rsh[t] = 0.f; wsh[t] = 2; }
    }
    __syncthreads();
    {
      int row = t >> 4, c0 = (t & 15) * 16;
      const float* yr = &y[nsh[row] * C_ + c0];
      float4 v0 = *(const float4*)&yr[0];
      float4 v1 = *(const float4*)&yr[4];
      float4 v2 = *(const float4*)&yr[8];
      float4 v3 = *(const float4*)&yr[12];
      *(float4*)&Ys[row][c0]      = v0;
      *(float4*)&Ys[row][c0 + 4]  = v1;
      *(float4*)&Ys[row][c0 + 8]  = v2;
      *(float4*)&Ys[row][c0 + 12] = v3;
    }
    int tx = t & 31, ty = t >> 5;
    int br = t >> 1, bk = (t & 1) * 16;
    float acc[2][4] = {};
    for (int k0 = 0; k0 < 256; k0 += 32) {
      const float* Brow = &cnew[(size_t)e * D_ + (size_t)(i0 + br) * C_ + k0 + bk];
      float4 b0 = *(const float4*)&Brow[0];
      float4 b1 = *(const float4*)&Brow[4];
      float4 b2 = *(const float4*)&Brow[8];
      float4 b3 = *(const float4*)&Brow[12];
      __syncthreads();
      Bs[bk+0][br]  = b0.x; Bs[bk+1][br]  = b0.y; Bs[bk+2][br]  = b0.z; Bs[bk+3][br]  = b0.w;
      Bs[bk+4][br]  = b1.x; Bs[bk+5][br]  = b1.y; Bs[bk+6][br]  = b1.z; Bs[bk+7][br]  = b1.w;
      Bs[bk+8][br]  = b2.x; Bs[bk+9][br]  = b2.y; Bs[bk+10][br] = b2.z; Bs[bk+11][br] = b2.w;
      Bs[bk+12][br] = b3.x; Bs[bk+13][br] = b3.y; Bs[bk+14][br] = b3.z; Bs[bk+15][br] = b3.w;
      __syncthreads();
      #pragma unroll
      for (int kk = 0; kk < 32; kk++) {
        float a0 = Ys[ty*2 + 0][k0 + kk];
        float a1 = Ys[ty*2 + 1][k0 + kk];
        float4 bv = *(const float4*)&Bs[kk][tx*4];
        acc[0][0] = fmaf(a0, bv.x, acc[0][0]); acc[0][1] = fmaf(a0, bv.y, acc[0][1]);
        acc[0][2] = fmaf(a0, bv.z, acc[0][2]); acc[0][3] = fmaf(a0, bv.w, acc[0][3]);
        acc[1][0] = fmaf(a1, bv.x, acc[1][0]); acc[1][1] = fmaf(a1, bv.y, acc[1][1]);
        acc[1][2] = fmaf(a1, bv.z, acc[1][2]); acc[1][3] = fmaf(a1, bv.w, acc[1][3]);
      }
    }
    #pragma unroll
    for (int i = 0; i < 2; i++) {
      int tk = ty*2 + i;
      float r = rsh[tk];
      if (r == 0.f) continue;
      int n = nsh[tk];
      float* op = &out[n * C_ + i0 + tx*4];
      if (wsh[tk] == 1) {
        float4 cur = *(const float4*)op;
        cur.x += r * acc[i][0]; cur.y += r * acc[i][1];
        cur.z += r * acc[i][2]; cur.w += r * acc[i][3];
        *(float4*)op = cur;
      } else {
        atomicAdd(op + 0, r * acc[i][0]);
        atomicAdd(op + 1, r * acc[i][1]);
        atomicAdd(op + 2, r * acc[i][2]);
        atomicAdd(op + 3, r * acc[i][3]);
      }
    }
  }
}

// ---- gsum = sum G .* S  (64 blocks; was the fat loop in single-block finalize)
__global__ __launch_bounds__(256) void k_gs(const float* __restrict__ G,
    const float* __restrict__ S, float* __restrict__ gsum) {
  int base = blockIdx.x * 1024 + threadIdx.x;
  float s = 0.f;
  #pragma unroll
  for (int q = 0; q < 4; q++) {
    int i = base + q * 256;
    s = fmaf(G[i], S[i], s);
  }
  __shared__ float red[256];
  red[threadIdx.x] = s;
  __syncthreads();
  for (int k = 128; k > 0; k >>= 1) {
    if (threadIdx.x < k) red[threadIdx.x] += red[threadIdx.x + k];
    __syncthreads();
  }
  if (threadIdx.x == 0) atomicAdd(gsum, red[0]);
}

// ---------------- loss assembly ----------------
__global__ __launch_bounds__(256) void k_finalize(
    const float* __restrict__ gsum, const float* __restrict__ M,
    const float* __restrict__ A, const float* __restrict__ AG,
    const float* __restrict__ CC0, const float* __restrict__ RR,
    const float* __restrict__ MA, const float* __restrict__ AGA,
    const float* __restrict__ Xsum, const float* __restrict__ Wb,
    const float* __restrict__ bb, const float* __restrict__ sr,
    const float* __restrict__ cb, const float* __restrict__ AWb,
    float* __restrict__ out) {
  int t = threadIdx.x;
  float a_gs = (t == 0) ? gsum[0] : 0.f;
  float a_am = 0.f, a_aag = 0.f;
  for (int i = t; i < 16384; i += 256) {
    float a = A[i];
    a_am  = fmaf(M[i], a, a_am);
    a_aag = fmaf(AG[i], a, a_aag);
  }
  float a_cc = 0.f, a_ma = 0.f, a_aga = 0.f, a_cbsr = 0.f, a_awbsr = 0.f, a_srsr = 0.f;
  for (int p = t; p < 4096; p += 256) {
    float r = RR[p];
    int e = p >> 6, f = p & 63;
    float srf = sr[f];
    a_cc    = fmaf(r, CC0[p], a_cc);
    a_ma    = fmaf(r, MA[p], a_ma);
    a_aga   = fmaf(r, AGA[p], a_aga);
    a_cbsr  = fmaf(r * cb[e], srf, a_cbsr);
    a_awbsr = fmaf(r * AWb[e], srf, a_awbsr);
    a_srsr  = fmaf(r * sr[e], srf, a_srsr);
  }
  float a_xw = Xsum[t] * Wb[t];
  float a_srcb = 0.f, a_srawb = 0.f, a_sr2 = 0.f;
  if (t < 64) { float s = sr[t]; a_srcb = s * cb[t]; a_srawb = s * AWb[t]; a_sr2 = s * s; }
  float v[13] = {a_gs, a_am, a_aag, a_cc, a_ma, a_aga, a_cbsr, a_awbsr, a_srsr,
                 a_xw, a_srcb, a_srawb, a_sr2};
  __shared__ float red[256];
  __shared__ float tot[13];
  for (int q = 0; q < 13; q++) {
    red[t] = v[q];
    __syncthreads();
    for (int s2 = 128; s2 > 0; s2 >>= 1) {
      if (t < s2) red[t] += red[t + s2];
      __syncthreads();
    }
    if (t == 0) tot[q] = red[0];
    __syncthreads();
  }
  if (t == 0) {
    const float q = DECAYF, al = ALPHA;
    float bbv = bb[0];
    float sumkeyf2 = tot[0] + 2.f * tot[9] + 2048.f * bbv;
    float cross = q * (tot[1] + tot[10]) + al * (tot[2] + 2.f * tot[11] + bbv * tot[12]);
    float sumq2 = q*q * tot[3] + 2.f*q*al * (tot[4] + tot[6])
                + al*al * (tot[5] + 2.f * tot[7] + bbv * tot[8]);
    out[524288] = (0.25f / (2048.0f * 65536.0f)) * (sumkeyf2 - 2.f * cross + sumq2);
  }
}

extern "C" void kernel_launch(void* const* d_in, const int* in_sizes, int n_in,
                              void* d_out, int out_size, void* d_ws, size_t ws_size,
                              hipStream_t stream) {
  const float* x    = (const float*)d_in[0];
  const float* u    = (const float*)d_in[1];
  const float* Wm   = (const float*)d_in[2];
  const float* bmap = (const float*)d_in[3];
  const float* pw   = (const float*)d_in[4];
  const float* pwB  = (const float*)d_in[5];
  const float* cen  = (const float*)d_in[6];
  float* out = (float*)d_out;
  float* ws  = (float*)d_ws;

  float* S_      = ws + OFF_S;
  float* Xsum    = ws + OFF_XSUM;
  float* G       = ws + OFF_G;
  float* M       = ws + OFF_M;
  float* Wb      = ws + OFF_WB;
  float* bb      = ws + OFF_BB;
  float* gsum    = ws + OFF_BB + 1;   // zero-init zone scalar
  float* sumresp = ws + OFF_SUMR;
  float* A       = ws + OFF_A;
  float* CC0     = ws + OFF_CC0;
  float* RR      = ws + OFF_RR;
  unsigned int* cnt = (unsigned int*)(ws + OFF_CNT);
  float* cn2     = ws + OFF_CN2;
  float* cb      = ws + OFF_CB;
  int*   tslot   = (int*)(ws + OFF_TSLOT);
  float* resp    = ws + OFF_RESP;
  float* AG      = ws + OFF_AG;
  float* MA      = ws + OFF_MA;
  float* AGA     = ws + OFF_AGA;
  float* AWb     = ws + OFF_AWB;
  int*   che     = (int*)(ws + OFF_CHE);
  int*   chb     = (int*)(ws + OFF_CHB);
  int*   nch     = (int*)(ws + OFF_NCH);
  float* y       = ws + OFF_Y;
  float* cnew    = ws + OFF_CNEW;
  float* scratch = ws + OFF_CNEW;     // k_G / k_M partials (pre-cnew, sequential)
  int*   tokidx  = (int*)(ws + OFF_TIDX);
  float* tokr    = ws + OFF_TOKR;

  hipMemsetAsync(d_ws, 0, ZFLOATS * sizeof(float), stream);

  k_cstats<<<256, 256, 0, stream>>>(cen, bmap, cn2, cb);
  k_bb<<<4, 256, 0, stream>>>(bmap, bb);
  k_S<<<dim3(8, 16), 256, 0, stream>>>(x, S_);
  k_xsum<<<32, 256, 0, stream>>>(x, Xsum);
  k_G<<<dim3(64, 3), 256, 0, stream>>>(Wm, scratch);
  k_Gred<<<dim3(64, 3), 256, 0, stream>>>(scratch, G);
  k_M<<<dim3(128, 4), 256, 0, stream>>>(cen, Wm, scratch);
  k_Mred<<<64, 256, 0, stream>>>(scratch, M);
  k_CC<<<128, 256, 0, stream>>>(cen, CC0);
  k_Wb<<<256, 256, 0, stream>>>(bmap, Wm, Wb);
  k_y<<<dim3(32, 4), 256, 0, stream>>>(x, pw, y);
  k_resp<<<2048, 64, 0, stream>>>(x, u, M, cn2, cb, resp);
  k_route<<<8, 256, 0, stream>>>(resp, cnt, tokidx, tokr, tslot);
  k_A2<<<dim3(8, 4), 256, 0, stream>>>(resp, x, A);
  k_sr<<<8, 256, 0, stream>>>(resp, sumresp);
  k_RR2<<<8, 256, 0, stream>>>(resp, RR);
  k_plan<<<1, 64, 0, stream>>>(cnt, che, chb, nch);
  k_ag<<<64, 256, 0, stream>>>(A, G, Wb, AG, AWb);
  k_small64<<<64, 256, 0, stream>>>(M, A, AG, MA, AGA);
  k_cnew<<<512, 256, 0, stream>>>(A, sumresp, cen, bmap, Wm, cnew);
  k_bias<<<2048, 256, 0, stream>>>(pwB, out);
  k_sA<<<dim3(SA_GRIDX, 2), 256, 0, stream>>>(che, chb, nch, cnt, tokidx, tokr,
                                              tslot, y, cnew, out);
  k_gs<<<64, 256, 0, stream>>>(G, S_, gsum);
  k_finalize<<<1, 256, 0, stream>>>(gsum, M, A, AG, CC0, RR, MA, AGA, Xsum, Wb,
                                    bb, sumresp, cb, AWb, out);
}